// Round 1
// baseline (1236.294 us; speedup 1.0000x reference)
//
#include <hip/hip_runtime.h>

typedef unsigned int u32;

// ---------------------------------------------------------------------------
// Edge-index dtype detection: if the buffer is int64 (little-endian, values
// < 2^31), every odd int32 slot is zero. If int32, odd slots are random
// node indices (P(all zero) ~ 0).
// ---------------------------------------------------------------------------
__global__ void k_detect(const int* __restrict__ p, int n_int32, u32* __restrict__ flag) {
    __shared__ int s[256];
    int tid = threadIdx.x;
    int acc = 0;
    int limit = n_int32 < 2048 ? n_int32 : 2048;
    for (int i = 1 + 2 * tid; i < limit; i += 512) acc |= p[i];
    s[tid] = acc;
    __syncthreads();
    for (int o = 128; o > 0; o >>= 1) {
        if (tid < o) s[tid] |= s[tid + o];
        __syncthreads();
    }
    if (tid == 0) *flag = (s[0] == 0) ? 1u : 0u;
}

__global__ void k_convert(const void* __restrict__ p, int n, const u32* __restrict__ flag,
                          int* __restrict__ out) {
    int i = blockIdx.x * blockDim.x + threadIdx.x;
    if (i >= n) return;
    if (*flag) out[i] = (int)((const long long*)p)[i];
    else       out[i] = ((const int*)p)[i];
}

// ---------------------------------------------------------------------------
// Degree / dinv / CSR build
// ---------------------------------------------------------------------------
__global__ void k_init(u32* __restrict__ deg, u32* __restrict__ cnt, int N) {
    int i = blockIdx.x * blockDim.x + threadIdx.x;
    if (i < N) { deg[i] = 1u; cnt[i] = 0u; }  // deg starts at 1 (self-loop)
}

__global__ void k_count(const int* __restrict__ dst, u32* __restrict__ deg, int E) {
    int e = blockIdx.x * blockDim.x + threadIdx.x;
    if (e < E) atomicAdd(&deg[dst[e]], 1u);
}

__global__ void k_dinv(const u32* __restrict__ deg, float* __restrict__ dinv, int N) {
    int i = blockIdx.x * blockDim.x + threadIdx.x;
    if (i < N) dinv[i] = rsqrtf((float)deg[i]);
}

// 3-phase exclusive scan of (deg[v]-1) -> row_ptr. Chunk = 1024 elems/block.
__global__ void k_scan_a(const u32* __restrict__ deg, u32* __restrict__ partial, int N) {
    __shared__ u32 s[256];
    int tid = threadIdx.x;
    int base = blockIdx.x * 1024 + tid * 4;
    u32 sum = 0;
#pragma unroll
    for (int j = 0; j < 4; ++j) {
        int v = base + j;
        sum += (v < N) ? (deg[v] - 1u) : 0u;
    }
    s[tid] = sum;
    __syncthreads();
    for (int o = 128; o > 0; o >>= 1) {
        if (tid < o) s[tid] += s[tid + o];
        __syncthreads();
    }
    if (tid == 0) partial[blockIdx.x] = s[0];
}

__global__ void k_scan_b(u32* __restrict__ partial, int NB, int* __restrict__ row_ptr, int N) {
    __shared__ u32 s[128];
    int tid = threadIdx.x;  // 128 threads
    u32 v = (tid < NB) ? partial[tid] : 0u;
    s[tid] = v;
    __syncthreads();
    for (int off = 1; off < 128; off <<= 1) {
        u32 t = (tid >= off) ? s[tid - off] : 0u;
        __syncthreads();
        s[tid] += t;
        __syncthreads();
    }
    if (tid < NB) partial[tid] = s[tid] - v;    // exclusive
    if (tid == 127) row_ptr[N] = (int)s[127];   // total = E
}

__global__ void k_scan_c(const u32* __restrict__ deg, const u32* __restrict__ partial,
                         int* __restrict__ row_ptr, int N) {
    __shared__ u32 s[256];
    int tid = threadIdx.x;
    int base = blockIdx.x * 1024 + tid * 4;
    u32 vals[4];
    u32 sum = 0;
#pragma unroll
    for (int j = 0; j < 4; ++j) {
        int v = base + j;
        vals[j] = (v < N) ? (deg[v] - 1u) : 0u;
        sum += vals[j];
    }
    s[tid] = sum;
    __syncthreads();
    for (int off = 1; off < 256; off <<= 1) {
        u32 t = (tid >= off) ? s[tid - off] : 0u;
        __syncthreads();
        s[tid] += t;
        __syncthreads();
    }
    u32 run = s[tid] - sum + partial[blockIdx.x];
#pragma unroll
    for (int j = 0; j < 4; ++j) {
        int v = base + j;
        if (v < N) row_ptr[v] = (int)run;
        run += vals[j];
    }
}

__global__ void k_fill(const int* __restrict__ src, const int* __restrict__ dst,
                       const int* __restrict__ row_ptr, u32* __restrict__ cnt,
                       int* __restrict__ col, int E) {
    int e = blockIdx.x * blockDim.x + threadIdx.x;
    if (e >= E) return;
    int d = dst[e];
    int pos = row_ptr[d] + (int)atomicAdd(&cnt[d], 1u);
    col[pos] = src[e];
}

// ---------------------------------------------------------------------------
// Weight transpose: Wt[k*COUT + o] = W[o*CIN + k]
// ---------------------------------------------------------------------------
template <int CIN, int COUT>
__global__ void k_transpose(const float* __restrict__ W, float* __restrict__ Wt) {
    int i = blockIdx.x * blockDim.x + threadIdx.x;
    if (i >= CIN * COUT) return;
    int k = i / COUT, o = i % COUT;
    Wt[i] = W[o * CIN + k];
}

// ---------------------------------------------------------------------------
// GEMM: G[row][o] = (sum_k X[row][k] * W[o][k]) * dinv[row]
// Wt staged in LDS as sW[k*COUT+o] (lanes vary o -> conflict-free).
// Block = 256 threads = 4 waves; 64 rows/block; each wave 16 rows, 4 at a time.
// ---------------------------------------------------------------------------
template <int CIN, int COUT>
__global__ __launch_bounds__(256) void k_gemm(const float* __restrict__ X,
                                              const float* __restrict__ Wt,
                                              const float* __restrict__ dinv,
                                              float* __restrict__ G, int N) {
    constexpr int OPL = COUT / 64;  // outputs per lane (1 or 2)
    __shared__ __align__(16) float sW[CIN * COUT];
    int tid = threadIdx.x;
    for (int i = 4 * tid; i < CIN * COUT; i += 4 * 256)
        *(float4*)&sW[i] = *(const float4*)&Wt[i];
    __syncthreads();

    int wid = tid >> 6, lane = tid & 63;
    int rowbase = blockIdx.x * 64 + wid * 16;

    for (int g = 0; g < 4; ++g) {
        int r0 = rowbase + g * 4;
        float acc[4][OPL];
#pragma unroll
        for (int r = 0; r < 4; ++r)
#pragma unroll
            for (int j = 0; j < OPL; ++j) acc[r][j] = 0.f;

        const float* xp[4];
#pragma unroll
        for (int r = 0; r < 4; ++r) {
            int row = r0 + r;
            if (row >= N) row = N - 1;  // clamp (store guarded below)
            xp[r] = X + (size_t)row * CIN;
        }

        for (int k = 0; k < CIN; k += 4) {
            float xr[4][4];
#pragma unroll
            for (int r = 0; r < 4; ++r) {
                float4 t = *(const float4*)(xp[r] + k);
                xr[r][0] = t.x; xr[r][1] = t.y; xr[r][2] = t.z; xr[r][3] = t.w;
            }
#pragma unroll
            for (int kk = 0; kk < 4; ++kk) {
#pragma unroll
                for (int j = 0; j < OPL; ++j) {
                    float w = sW[(k + kk) * COUT + j * 64 + lane];
#pragma unroll
                    for (int r = 0; r < 4; ++r) acc[r][j] += xr[r][kk] * w;
                }
            }
        }

#pragma unroll
        for (int r = 0; r < 4; ++r) {
            int row = r0 + r;
            if (row < N) {
                float s = dinv[row];
#pragma unroll
                for (int j = 0; j < OPL; ++j)
                    G[(size_t)row * COUT + j * 64 + lane] = acc[r][j] * s;
            }
        }
    }
}

// ---------------------------------------------------------------------------
// SpMM: Y[v][c] = act( dinv[v] * (G[v][c] + sum_{e in row v} G[col[e]][c]) + b[c] )
// One wave per node; lane covers 2 channels (COUT=128) or 1 (COUT=64).
// ---------------------------------------------------------------------------
template <int COUT, bool RELU>
__global__ __launch_bounds__(256) void k_spmm(const float* __restrict__ G,
                                              const int* __restrict__ rp,
                                              const int* __restrict__ col,
                                              const float* __restrict__ dinv,
                                              const float* __restrict__ bias,
                                              float* __restrict__ Y, int N) {
    int wid = threadIdx.x >> 6, lane = threadIdx.x & 63;
    int v = blockIdx.x * 4 + wid;
    if (v >= N) return;

    if (COUT == 128) {
        float2 acc = *(const float2*)(G + (size_t)v * 128 + 2 * lane);
        int e = rp[v], end = rp[v + 1];
        for (; e + 4 <= end; e += 4) {
            int u0 = col[e], u1 = col[e + 1], u2 = col[e + 2], u3 = col[e + 3];
            float2 a0 = *(const float2*)(G + (size_t)u0 * 128 + 2 * lane);
            float2 a1 = *(const float2*)(G + (size_t)u1 * 128 + 2 * lane);
            float2 a2 = *(const float2*)(G + (size_t)u2 * 128 + 2 * lane);
            float2 a3 = *(const float2*)(G + (size_t)u3 * 128 + 2 * lane);
            acc.x += a0.x + a1.x + a2.x + a3.x;
            acc.y += a0.y + a1.y + a2.y + a3.y;
        }
        for (; e < end; ++e) {
            int u = col[e];
            float2 a = *(const float2*)(G + (size_t)u * 128 + 2 * lane);
            acc.x += a.x; acc.y += a.y;
        }
        float s = dinv[v];
        float rx = acc.x * s + bias[2 * lane];
        float ry = acc.y * s + bias[2 * lane + 1];
        if (RELU) { rx = fmaxf(rx, 0.f); ry = fmaxf(ry, 0.f); }
        float2 out; out.x = rx; out.y = ry;
        *(float2*)(Y + (size_t)v * 128 + 2 * lane) = out;
    } else {  // COUT == 64
        float acc = G[(size_t)v * 64 + lane];
        int e = rp[v], end = rp[v + 1];
        for (; e + 4 <= end; e += 4) {
            int u0 = col[e], u1 = col[e + 1], u2 = col[e + 2], u3 = col[e + 3];
            float a0 = G[(size_t)u0 * 64 + lane];
            float a1 = G[(size_t)u1 * 64 + lane];
            float a2 = G[(size_t)u2 * 64 + lane];
            float a3 = G[(size_t)u3 * 64 + lane];
            acc += a0 + a1 + a2 + a3;
        }
        for (; e < end; ++e) acc += G[(size_t)col[e] * 64 + lane];
        float s = dinv[v];
        float r = acc * s + bias[lane];
        if (RELU) r = fmaxf(r, 0.f);
        Y[(size_t)v * 64 + lane] = r;
    }
}

// ---------------------------------------------------------------------------
extern "C" void kernel_launch(void* const* d_in, const int* in_sizes, int n_in,
                              void* d_out, int out_size, void* d_ws, size_t ws_size,
                              hipStream_t stream) {
    const float* x  = (const float*)d_in[0];
    const void*  ei = d_in[1];
    const float* W1 = (const float*)d_in[2];
    const float* b1 = (const float*)d_in[3];
    const float* W2 = (const float*)d_in[4];
    const float* b2 = (const float*)d_in[5];
    const float* W3 = (const float*)d_in[6];
    const float* b3 = (const float*)d_in[7];
    const float* W4 = (const float*)d_in[8];
    const float* b4 = (const float*)d_in[9];

    const int N = in_sizes[0] / 128;   // 100000
    const int E = in_sizes[1] / 2;     // 1600000

    // workspace carve-up (256B aligned)
    size_t off = 0;
    auto alloc = [&](size_t bytes) -> void* {
        void* p = (char*)d_ws + off;
        off += (bytes + 255) & ~(size_t)255;
        return p;
    };
    u32*   flag    = (u32*)  alloc(4);
    int*   src32   = (int*)  alloc((size_t)E * 4);
    int*   dst32   = (int*)  alloc((size_t)E * 4);
    u32*   deg     = (u32*)  alloc((size_t)N * 4);
    float* dinv    = (float*)alloc((size_t)N * 4);
    int*   row_ptr = (int*)  alloc((size_t)(N + 1) * 4);
    u32*   cnt     = (u32*)  alloc((size_t)N * 4);
    u32*   partial = (u32*)  alloc(256 * 4);
    int*   col     = (int*)  alloc((size_t)E * 4);
    float* Wt      = (float*)alloc(128 * 128 * 4);
    float* A       = (float*)alloc((size_t)N * 128 * 4);  // G' buffer
    float* B       = (float*)alloc((size_t)N * 128 * 4);  // layer outputs
    float* Z       = (float*)d_out;                        // 64-ch bottleneck reuses d_out

    const int n2 = 2 * E;
    const int NB = (N + 1023) / 1024;

    // graph preprocessing
    k_detect<<<1, 256, 0, stream>>>((const int*)ei, n2, flag);
    k_convert<<<(n2 + 255) / 256, 256, 0, stream>>>(ei, n2, flag, src32);  // src32[0..E)=src, [E..2E)=dst
    int* dstp = src32 + E;
    k_init<<<(N + 255) / 256, 256, 0, stream>>>(deg, cnt, N);
    k_count<<<(E + 255) / 256, 256, 0, stream>>>(dstp, deg, E);
    k_dinv<<<(N + 255) / 256, 256, 0, stream>>>(deg, dinv, N);
    k_scan_a<<<NB, 256, 0, stream>>>(deg, partial, N);
    k_scan_b<<<1, 128, 0, stream>>>(partial, NB, row_ptr, N);
    k_scan_c<<<NB, 256, 0, stream>>>(deg, partial, row_ptr, N);
    k_fill<<<(E + 255) / 256, 256, 0, stream>>>(src32, dstp, row_ptr, cnt, col, E);
    (void)dst32;

    const int gG = (N + 63) / 64;    // gemm grid
    const int gS = (N + 3) / 4;      // spmm grid

    // Layer 1: x[128] -> h1[128], relu
    k_transpose<128, 128><<<(128 * 128 + 255) / 256, 256, 0, stream>>>(W1, Wt);
    k_gemm<128, 128><<<gG, 256, 0, stream>>>(x, Wt, dinv, A, N);
    k_spmm<128, true><<<gS, 256, 0, stream>>>(A, row_ptr, col, dinv, b1, B, N);

    // Layer 2: h1[128] -> z[64]
    k_transpose<128, 64><<<(128 * 64 + 255) / 256, 256, 0, stream>>>(W2, Wt);
    k_gemm<128, 64><<<gG, 256, 0, stream>>>(B, Wt, dinv, A, N);
    k_spmm<64, false><<<gS, 256, 0, stream>>>(A, row_ptr, col, dinv, b2, Z, N);

    // Layer 3: z[64] -> h3[128], relu
    k_transpose<64, 128><<<(64 * 128 + 255) / 256, 256, 0, stream>>>(W3, Wt);
    k_gemm<64, 128><<<gG, 256, 0, stream>>>(Z, Wt, dinv, A, N);
    k_spmm<128, true><<<gS, 256, 0, stream>>>(A, row_ptr, col, dinv, b3, B, N);

    // Layer 4: h3[128] -> out[128]
    k_transpose<128, 128><<<(128 * 128 + 255) / 256, 256, 0, stream>>>(W4, Wt);
    k_gemm<128, 128><<<gG, 256, 0, stream>>>(B, Wt, dinv, A, N);
    k_spmm<128, false><<<gS, 256, 0, stream>>>(A, row_ptr, col, dinv, b4, (float*)d_out, N);
}

// Round 2
// 905.451 us; speedup vs baseline: 1.3654x; 1.3654x over previous
//
#include <hip/hip_runtime.h>

typedef unsigned int u32;

// ---------------------------------------------------------------------------
// Edge-index dtype detection: if the buffer is int64 (little-endian, values
// < 2^31), every odd int32 slot is zero. If int32, odd slots are random
// node indices (P(all zero) ~ 0).
// ---------------------------------------------------------------------------
__global__ void k_detect(const int* __restrict__ p, int n_int32, u32* __restrict__ flag) {
    __shared__ int s[256];
    int tid = threadIdx.x;
    int acc = 0;
    int limit = n_int32 < 2048 ? n_int32 : 2048;
    for (int i = 1 + 2 * tid; i < limit; i += 512) acc |= p[i];
    s[tid] = acc;
    __syncthreads();
    for (int o = 128; o > 0; o >>= 1) {
        if (tid < o) s[tid] |= s[tid + o];
        __syncthreads();
    }
    if (tid == 0) *flag = (s[0] == 0) ? 1u : 0u;
}

__global__ void k_convert(const void* __restrict__ p, int n, const u32* __restrict__ flag,
                          int* __restrict__ out) {
    int i = blockIdx.x * blockDim.x + threadIdx.x;
    if (i >= n) return;
    if (*flag) out[i] = (int)((const long long*)p)[i];
    else       out[i] = ((const int*)p)[i];
}

// ---------------------------------------------------------------------------
// Degree / dinv / CSR build
// ---------------------------------------------------------------------------
__global__ void k_init(u32* __restrict__ deg, u32* __restrict__ cnt, int N) {
    int i = blockIdx.x * blockDim.x + threadIdx.x;
    if (i < N) { deg[i] = 1u; cnt[i] = 0u; }  // deg starts at 1 (self-loop)
}

__global__ void k_count(const int* __restrict__ dst, u32* __restrict__ deg, int E) {
    int e = blockIdx.x * blockDim.x + threadIdx.x;
    if (e < E) atomicAdd(&deg[dst[e]], 1u);
}

__global__ void k_dinv(const u32* __restrict__ deg, float* __restrict__ dinv, int N) {
    int i = blockIdx.x * blockDim.x + threadIdx.x;
    if (i < N) dinv[i] = rsqrtf((float)deg[i]);
}

// 3-phase exclusive scan of (deg[v]-1) -> row_ptr. Chunk = 1024 elems/block.
__global__ void k_scan_a(const u32* __restrict__ deg, u32* __restrict__ partial, int N) {
    __shared__ u32 s[256];
    int tid = threadIdx.x;
    int base = blockIdx.x * 1024 + tid * 4;
    u32 sum = 0;
#pragma unroll
    for (int j = 0; j < 4; ++j) {
        int v = base + j;
        sum += (v < N) ? (deg[v] - 1u) : 0u;
    }
    s[tid] = sum;
    __syncthreads();
    for (int o = 128; o > 0; o >>= 1) {
        if (tid < o) s[tid] += s[tid + o];
        __syncthreads();
    }
    if (tid == 0) partial[blockIdx.x] = s[0];
}

__global__ void k_scan_b(u32* __restrict__ partial, int NB, int* __restrict__ row_ptr, int N) {
    __shared__ u32 s[128];
    int tid = threadIdx.x;  // 128 threads
    u32 v = (tid < NB) ? partial[tid] : 0u;
    s[tid] = v;
    __syncthreads();
    for (int off = 1; off < 128; off <<= 1) {
        u32 t = (tid >= off) ? s[tid - off] : 0u;
        __syncthreads();
        s[tid] += t;
        __syncthreads();
    }
    if (tid < NB) partial[tid] = s[tid] - v;    // exclusive
    if (tid == 127) row_ptr[N] = (int)s[127];   // total = E
}

__global__ void k_scan_c(const u32* __restrict__ deg, const u32* __restrict__ partial,
                         int* __restrict__ row_ptr, int N) {
    __shared__ u32 s[256];
    int tid = threadIdx.x;
    int base = blockIdx.x * 1024 + tid * 4;
    u32 vals[4];
    u32 sum = 0;
#pragma unroll
    for (int j = 0; j < 4; ++j) {
        int v = base + j;
        vals[j] = (v < N) ? (deg[v] - 1u) : 0u;
        sum += vals[j];
    }
    s[tid] = sum;
    __syncthreads();
    for (int off = 1; off < 256; off <<= 1) {
        u32 t = (tid >= off) ? s[tid - off] : 0u;
        __syncthreads();
        s[tid] += t;
        __syncthreads();
    }
    u32 run = s[tid] - sum + partial[blockIdx.x];
#pragma unroll
    for (int j = 0; j < 4; ++j) {
        int v = base + j;
        if (v < N) row_ptr[v] = (int)run;
        run += vals[j];
    }
}

__global__ void k_fill(const int* __restrict__ src, const int* __restrict__ dst,
                       const int* __restrict__ row_ptr, u32* __restrict__ cnt,
                       int* __restrict__ col, int E) {
    int e = blockIdx.x * blockDim.x + threadIdx.x;
    if (e >= E) return;
    int d = dst[e];
    int pos = row_ptr[d] + (int)atomicAdd(&cnt[d], 1u);
    col[pos] = src[e];
}

// ---------------------------------------------------------------------------
// Weight transpose: Wt[k*COUT + o] = W[o*CIN + k]
// ---------------------------------------------------------------------------
template <int CIN, int COUT>
__global__ void k_transpose(const float* __restrict__ W, float* __restrict__ Wt) {
    int i = blockIdx.x * blockDim.x + threadIdx.x;
    if (i >= CIN * COUT) return;
    int k = i / COUT, o = i % COUT;
    Wt[i] = W[o * CIN + k];
}

// ---------------------------------------------------------------------------
// GEMM v2: G[row][o] = (sum_k X[row][k] * W[o][k]) * dinv[row]
// Block = 256 thr (4 waves) = 64 rows. K processed in chunks of KC<=64.
// Both X row-tile and W k-chunk staged in LDS; inner loop is LDS+FMA only.
//   sW[k][o]   : lane-consecutive reads (o = lane + 64j) -> 2-way = free
//   sX[r][k]   : wave-uniform broadcast b128 reads -> free
// Each wave register-blocks 16 rows x OPL outputs: acc = 16*OPL VGPRs.
// ---------------------------------------------------------------------------
template <int CIN, int COUT>
__global__ __launch_bounds__(256) void k_gemm(const float* __restrict__ X,
                                              const float* __restrict__ Wt,
                                              const float* __restrict__ dinv,
                                              float* __restrict__ G, int N) {
    constexpr int OPL = COUT / 64;           // outputs per lane (1 or 2)
    constexpr int KC = (CIN < 64) ? CIN : 64;
    constexpr int XPITCH = KC + 4;           // pad: break stage-write conflicts
    __shared__ __align__(16) float sW[KC * COUT];
    __shared__ __align__(16) float sX[64 * XPITCH];

    int tid = threadIdx.x, wid = tid >> 6, lane = tid & 63;
    int rowbase = blockIdx.x * 64;

    float acc[16][OPL];
#pragma unroll
    for (int r = 0; r < 16; ++r)
#pragma unroll
        for (int j = 0; j < OPL; ++j) acc[r][j] = 0.f;

    for (int k0 = 0; k0 < CIN; k0 += KC) {
        __syncthreads();  // protect previous chunk's reads before overwrite
        // stage W chunk: contiguous region of Wt
        for (int i = 4 * tid; i < KC * COUT; i += 1024)
            *(float4*)&sW[i] = *(const float4*)&Wt[(size_t)k0 * COUT + i];
        // stage X tile: 64 rows x KC cols; 4 threads per row, 16 floats each
        {
            int r = tid >> 2, p = tid & 3;
            int row = rowbase + r;
            if (row >= N) row = N - 1;       // clamp (stores guarded later)
            const float4* xp = (const float4*)(X + (size_t)row * CIN + k0 + p * 16);
            float* sp = &sX[r * XPITCH + p * 16];
#pragma unroll
            for (int j = 0; j < 4; ++j) *(float4*)(sp + 4 * j) = xp[j];
        }
        __syncthreads();

        const float* sXw = &sX[wid * 16 * XPITCH];
#pragma unroll 4
        for (int k = 0; k < KC; k += 4) {
            float w[4][OPL];
#pragma unroll
            for (int kk = 0; kk < 4; ++kk)
#pragma unroll
                for (int j = 0; j < OPL; ++j)
                    w[kk][j] = sW[(k + kk) * COUT + j * 64 + lane];
#pragma unroll
            for (int r = 0; r < 16; ++r) {
                float4 xv = *(const float4*)&sXw[r * XPITCH + k];
#pragma unroll
                for (int j = 0; j < OPL; ++j) {
                    acc[r][j] += xv.x * w[0][j];
                    acc[r][j] += xv.y * w[1][j];
                    acc[r][j] += xv.z * w[2][j];
                    acc[r][j] += xv.w * w[3][j];
                }
            }
        }
    }

    // epilogue: scale by dinv[row], store
#pragma unroll
    for (int r = 0; r < 16; ++r) {
        int row = rowbase + wid * 16 + r;
        if (row < N) {
            float s = dinv[row];
#pragma unroll
            for (int j = 0; j < OPL; ++j)
                G[(size_t)row * COUT + j * 64 + lane] = acc[r][j] * s;
        }
    }
}

// ---------------------------------------------------------------------------
// SpMM: Y[v][c] = act( dinv[v] * (G[v][c] + sum_{e in row v} G[col[e]][c]) + b[c] )
// One wave per node; lane covers 2 channels (COUT=128) or 1 (COUT=64).
// ---------------------------------------------------------------------------
template <int COUT, bool RELU>
__global__ __launch_bounds__(256) void k_spmm(const float* __restrict__ G,
                                              const int* __restrict__ rp,
                                              const int* __restrict__ col,
                                              const float* __restrict__ dinv,
                                              const float* __restrict__ bias,
                                              float* __restrict__ Y, int N) {
    int wid = threadIdx.x >> 6, lane = threadIdx.x & 63;
    int v = blockIdx.x * 4 + wid;
    if (v >= N) return;

    if (COUT == 128) {
        float2 acc = *(const float2*)(G + (size_t)v * 128 + 2 * lane);
        int e = rp[v], end = rp[v + 1];
        for (; e + 4 <= end; e += 4) {
            int u0 = col[e], u1 = col[e + 1], u2 = col[e + 2], u3 = col[e + 3];
            float2 a0 = *(const float2*)(G + (size_t)u0 * 128 + 2 * lane);
            float2 a1 = *(const float2*)(G + (size_t)u1 * 128 + 2 * lane);
            float2 a2 = *(const float2*)(G + (size_t)u2 * 128 + 2 * lane);
            float2 a3 = *(const float2*)(G + (size_t)u3 * 128 + 2 * lane);
            acc.x += a0.x + a1.x + a2.x + a3.x;
            acc.y += a0.y + a1.y + a2.y + a3.y;
        }
        for (; e < end; ++e) {
            int u = col[e];
            float2 a = *(const float2*)(G + (size_t)u * 128 + 2 * lane);
            acc.x += a.x; acc.y += a.y;
        }
        float s = dinv[v];
        float rx = acc.x * s + bias[2 * lane];
        float ry = acc.y * s + bias[2 * lane + 1];
        if (RELU) { rx = fmaxf(rx, 0.f); ry = fmaxf(ry, 0.f); }
        float2 out; out.x = rx; out.y = ry;
        *(float2*)(Y + (size_t)v * 128 + 2 * lane) = out;
    } else {  // COUT == 64
        float acc = G[(size_t)v * 64 + lane];
        int e = rp[v], end = rp[v + 1];
        for (; e + 4 <= end; e += 4) {
            int u0 = col[e], u1 = col[e + 1], u2 = col[e + 2], u3 = col[e + 3];
            float a0 = G[(size_t)u0 * 64 + lane];
            float a1 = G[(size_t)u1 * 64 + lane];
            float a2 = G[(size_t)u2 * 64 + lane];
            float a3 = G[(size_t)u3 * 64 + lane];
            acc += a0 + a1 + a2 + a3;
        }
        for (; e < end; ++e) acc += G[(size_t)col[e] * 64 + lane];
        float s = dinv[v];
        float r = acc * s + bias[lane];
        if (RELU) r = fmaxf(r, 0.f);
        Y[(size_t)v * 64 + lane] = r;
    }
}

// ---------------------------------------------------------------------------
extern "C" void kernel_launch(void* const* d_in, const int* in_sizes, int n_in,
                              void* d_out, int out_size, void* d_ws, size_t ws_size,
                              hipStream_t stream) {
    const float* x  = (const float*)d_in[0];
    const void*  ei = d_in[1];
    const float* W1 = (const float*)d_in[2];
    const float* b1 = (const float*)d_in[3];
    const float* W2 = (const float*)d_in[4];
    const float* b2 = (const float*)d_in[5];
    const float* W3 = (const float*)d_in[6];
    const float* b3 = (const float*)d_in[7];
    const float* W4 = (const float*)d_in[8];
    const float* b4 = (const float*)d_in[9];

    const int N = in_sizes[0] / 128;   // 100000
    const int E = in_sizes[1] / 2;     // 1600000

    // workspace carve-up (256B aligned)
    size_t off = 0;
    auto alloc = [&](size_t bytes) -> void* {
        void* p = (char*)d_ws + off;
        off += (bytes + 255) & ~(size_t)255;
        return p;
    };
    u32*   flag    = (u32*)  alloc(4);
    int*   src32   = (int*)  alloc((size_t)E * 4);
    int*   dst32   = (int*)  alloc((size_t)E * 4);
    u32*   deg     = (u32*)  alloc((size_t)N * 4);
    float* dinv    = (float*)alloc((size_t)N * 4);
    int*   row_ptr = (int*)  alloc((size_t)(N + 1) * 4);
    u32*   cnt     = (u32*)  alloc((size_t)N * 4);
    u32*   partial = (u32*)  alloc(256 * 4);
    int*   col     = (int*)  alloc((size_t)E * 4);
    float* Wt      = (float*)alloc(128 * 128 * 4);
    float* A       = (float*)alloc((size_t)N * 128 * 4);  // G' buffer
    float* B       = (float*)alloc((size_t)N * 128 * 4);  // layer outputs
    float* Z       = (float*)d_out;                        // 64-ch bottleneck reuses d_out

    const int n2 = 2 * E;
    const int NB = (N + 1023) / 1024;

    // graph preprocessing
    k_detect<<<1, 256, 0, stream>>>((const int*)ei, n2, flag);
    k_convert<<<(n2 + 255) / 256, 256, 0, stream>>>(ei, n2, flag, src32);  // src32[0..E)=src, [E..2E)=dst
    int* dstp = src32 + E;
    k_init<<<(N + 255) / 256, 256, 0, stream>>>(deg, cnt, N);
    k_count<<<(E + 255) / 256, 256, 0, stream>>>(dstp, deg, E);
    k_dinv<<<(N + 255) / 256, 256, 0, stream>>>(deg, dinv, N);
    k_scan_a<<<NB, 256, 0, stream>>>(deg, partial, N);
    k_scan_b<<<1, 128, 0, stream>>>(partial, NB, row_ptr, N);
    k_scan_c<<<NB, 256, 0, stream>>>(deg, partial, row_ptr, N);
    k_fill<<<(E + 255) / 256, 256, 0, stream>>>(src32, dstp, row_ptr, cnt, col, E);
    (void)dst32;

    const int gG = (N + 63) / 64;    // gemm grid
    const int gS = (N + 3) / 4;      // spmm grid

    // Layer 1: x[128] -> h1[128], relu
    k_transpose<128, 128><<<(128 * 128 + 255) / 256, 256, 0, stream>>>(W1, Wt);
    k_gemm<128, 128><<<gG, 256, 0, stream>>>(x, Wt, dinv, A, N);
    k_spmm<128, true><<<gS, 256, 0, stream>>>(A, row_ptr, col, dinv, b1, B, N);

    // Layer 2: h1[128] -> z[64]
    k_transpose<128, 64><<<(128 * 64 + 255) / 256, 256, 0, stream>>>(W2, Wt);
    k_gemm<128, 64><<<gG, 256, 0, stream>>>(B, Wt, dinv, A, N);
    k_spmm<64, false><<<gS, 256, 0, stream>>>(A, row_ptr, col, dinv, b2, Z, N);

    // Layer 3: z[64] -> h3[128], relu
    k_transpose<64, 128><<<(64 * 128 + 255) / 256, 256, 0, stream>>>(W3, Wt);
    k_gemm<64, 128><<<gG, 256, 0, stream>>>(Z, Wt, dinv, A, N);
    k_spmm<128, true><<<gS, 256, 0, stream>>>(A, row_ptr, col, dinv, b3, B, N);

    // Layer 4: h3[128] -> out[128]
    k_transpose<128, 128><<<(128 * 128 + 255) / 256, 256, 0, stream>>>(W4, Wt);
    k_gemm<128, 128><<<gG, 256, 0, stream>>>(B, Wt, dinv, A, N);
    k_spmm<128, false><<<gS, 256, 0, stream>>>(A, row_ptr, col, dinv, b4, (float*)d_out, N);
}

// Round 3
// 831.797 us; speedup vs baseline: 1.4863x; 1.0885x over previous
//
#include <hip/hip_runtime.h>

typedef unsigned int u32;
using v2f = __attribute__((ext_vector_type(2))) float;

// ---------------------------------------------------------------------------
// Edge-index dtype detection: if the buffer is int64 (little-endian, values
// < 2^31), every odd int32 slot is zero. If int32, odd slots are random
// node indices (P(all zero) ~ 0).
// ---------------------------------------------------------------------------
__global__ void k_detect(const int* __restrict__ p, int n_int32, u32* __restrict__ flag) {
    __shared__ int s[256];
    int tid = threadIdx.x;
    int acc = 0;
    int limit = n_int32 < 2048 ? n_int32 : 2048;
    for (int i = 1 + 2 * tid; i < limit; i += 512) acc |= p[i];
    s[tid] = acc;
    __syncthreads();
    for (int o = 128; o > 0; o >>= 1) {
        if (tid < o) s[tid] |= s[tid + o];
        __syncthreads();
    }
    if (tid == 0) *flag = (s[0] == 0) ? 1u : 0u;
}

__global__ void k_convert(const void* __restrict__ p, int n, const u32* __restrict__ flag,
                          int* __restrict__ out) {
    int i = blockIdx.x * blockDim.x + threadIdx.x;
    if (i >= n) return;
    if (*flag) out[i] = (int)((const long long*)p)[i];
    else       out[i] = ((const int*)p)[i];
}

// ---------------------------------------------------------------------------
// Degree / dinv / CSR build
// ---------------------------------------------------------------------------
__global__ void k_init(u32* __restrict__ deg, u32* __restrict__ cnt, int N) {
    int i = blockIdx.x * blockDim.x + threadIdx.x;
    if (i < N) { deg[i] = 1u; cnt[i] = 0u; }  // deg starts at 1 (self-loop)
}

__global__ void k_count(const int* __restrict__ dst, u32* __restrict__ deg, int E) {
    int e = blockIdx.x * blockDim.x + threadIdx.x;
    if (e < E) atomicAdd(&deg[dst[e]], 1u);
}

__global__ void k_dinv(const u32* __restrict__ deg, float* __restrict__ dinv, int N) {
    int i = blockIdx.x * blockDim.x + threadIdx.x;
    if (i < N) dinv[i] = rsqrtf((float)deg[i]);
}

// 3-phase exclusive scan of (deg[v]-1) -> row_ptr. Chunk = 1024 elems/block.
__global__ void k_scan_a(const u32* __restrict__ deg, u32* __restrict__ partial, int N) {
    __shared__ u32 s[256];
    int tid = threadIdx.x;
    int base = blockIdx.x * 1024 + tid * 4;
    u32 sum = 0;
#pragma unroll
    for (int j = 0; j < 4; ++j) {
        int v = base + j;
        sum += (v < N) ? (deg[v] - 1u) : 0u;
    }
    s[tid] = sum;
    __syncthreads();
    for (int o = 128; o > 0; o >>= 1) {
        if (tid < o) s[tid] += s[tid + o];
        __syncthreads();
    }
    if (tid == 0) partial[blockIdx.x] = s[0];
}

__global__ void k_scan_b(u32* __restrict__ partial, int NB, int* __restrict__ row_ptr, int N) {
    __shared__ u32 s[128];
    int tid = threadIdx.x;  // 128 threads
    u32 v = (tid < NB) ? partial[tid] : 0u;
    s[tid] = v;
    __syncthreads();
    for (int off = 1; off < 128; off <<= 1) {
        u32 t = (tid >= off) ? s[tid - off] : 0u;
        __syncthreads();
        s[tid] += t;
        __syncthreads();
    }
    if (tid < NB) partial[tid] = s[tid] - v;    // exclusive
    if (tid == 127) row_ptr[N] = (int)s[127];   // total = E
}

__global__ void k_scan_c(const u32* __restrict__ deg, const u32* __restrict__ partial,
                         int* __restrict__ row_ptr, int N) {
    __shared__ u32 s[256];
    int tid = threadIdx.x;
    int base = blockIdx.x * 1024 + tid * 4;
    u32 vals[4];
    u32 sum = 0;
#pragma unroll
    for (int j = 0; j < 4; ++j) {
        int v = base + j;
        vals[j] = (v < N) ? (deg[v] - 1u) : 0u;
        sum += vals[j];
    }
    s[tid] = sum;
    __syncthreads();
    for (int off = 1; off < 256; off <<= 1) {
        u32 t = (tid >= off) ? s[tid - off] : 0u;
        __syncthreads();
        s[tid] += t;
        __syncthreads();
    }
    u32 run = s[tid] - sum + partial[blockIdx.x];
#pragma unroll
    for (int j = 0; j < 4; ++j) {
        int v = base + j;
        if (v < N) row_ptr[v] = (int)run;
        run += vals[j];
    }
}

__global__ void k_fill(const int* __restrict__ src, const int* __restrict__ dst,
                       const int* __restrict__ row_ptr, u32* __restrict__ cnt,
                       int* __restrict__ col, int E) {
    int e = blockIdx.x * blockDim.x + threadIdx.x;
    if (e >= E) return;
    int d = dst[e];
    int pos = row_ptr[d] + (int)atomicAdd(&cnt[d], 1u);
    col[pos] = src[e];
}

// ---------------------------------------------------------------------------
// Weight transpose: Wt[k*COUT + o] = W[o*CIN + k]
// ---------------------------------------------------------------------------
template <int CIN, int COUT>
__global__ void k_transpose(const float* __restrict__ W, float* __restrict__ Wt) {
    int i = blockIdx.x * blockDim.x + threadIdx.x;
    if (i >= CIN * COUT) return;
    int k = i / COUT, o = i % COUT;
    Wt[i] = W[o * CIN + k];
}

// ---------------------------------------------------------------------------
// GEMM: out[row][o] = epilogue( sum_k X[row][k] * W[o][k] )
//   MODE 0: out = acc * dinv[row]            (aux = dinv)
//   MODE 1: out = relu(acc + bias[o])        (aux = bias)
// Block = 256 thr (4 waves) = 64 rows. K chunks of KC<=64 staged in LDS.
// Inner loop packs k in float2 pairs -> candidate for v_pk_fma_f32.
// ---------------------------------------------------------------------------
template <int CIN, int COUT, int MODE>
__global__ __launch_bounds__(256) void k_gemm(const float* __restrict__ X,
                                              const float* __restrict__ Wt,
                                              const float* __restrict__ aux,
                                              float* __restrict__ G, int N) {
    constexpr int OPL = COUT / 64;           // outputs per lane (1 or 2)
    constexpr int KC = (CIN < 64) ? CIN : 64;
    constexpr int XPITCH = KC + 4;           // pad: break stage-write conflicts
    __shared__ __align__(16) float sW[KC * COUT];
    __shared__ __align__(16) float sX[64 * XPITCH];

    int tid = threadIdx.x, wid = tid >> 6, lane = tid & 63;
    int rowbase = blockIdx.x * 64;

    v2f acc2[16][OPL];
#pragma unroll
    for (int r = 0; r < 16; ++r)
#pragma unroll
        for (int j = 0; j < OPL; ++j) acc2[r][j] = (v2f){0.f, 0.f};

    for (int k0 = 0; k0 < CIN; k0 += KC) {
        __syncthreads();  // protect previous chunk's reads before overwrite
        // stage W chunk: contiguous region of Wt
        for (int i = 4 * tid; i < KC * COUT; i += 1024)
            *(float4*)&sW[i] = *(const float4*)&Wt[(size_t)k0 * COUT + i];
        // stage X tile: 64 rows x KC cols; 4 threads per row, 16 floats each
        {
            int r = tid >> 2, p = tid & 3;
            int row = rowbase + r;
            if (row >= N) row = N - 1;       // clamp (stores guarded later)
            const float4* xp = (const float4*)(X + (size_t)row * CIN + k0 + p * 16);
            float* sp = &sX[r * XPITCH + p * 16];
#pragma unroll
            for (int j = 0; j < 4; ++j) *(float4*)(sp + 4 * j) = xp[j];
        }
        __syncthreads();

        const float* sXw = &sX[wid * 16 * XPITCH];
#pragma unroll 4
        for (int k = 0; k < KC; k += 4) {
            v2f w01[OPL], w23[OPL];
#pragma unroll
            for (int j = 0; j < OPL; ++j) {
                w01[j] = (v2f){sW[(k + 0) * COUT + j * 64 + lane],
                               sW[(k + 1) * COUT + j * 64 + lane]};
                w23[j] = (v2f){sW[(k + 2) * COUT + j * 64 + lane],
                               sW[(k + 3) * COUT + j * 64 + lane]};
            }
#pragma unroll
            for (int r = 0; r < 16; ++r) {
                float4 xv = *(const float4*)&sXw[r * XPITCH + k];
                v2f x01 = (v2f){xv.x, xv.y};
                v2f x23 = (v2f){xv.z, xv.w};
#pragma unroll
                for (int j = 0; j < OPL; ++j) {
                    acc2[r][j] += x01 * w01[j];
                    acc2[r][j] += x23 * w23[j];
                }
            }
        }
    }

    // epilogue
    float bv[OPL];
    if (MODE == 1) {
#pragma unroll
        for (int j = 0; j < OPL; ++j) bv[j] = aux[j * 64 + lane];
    }
#pragma unroll
    for (int r = 0; r < 16; ++r) {
        int row = rowbase + wid * 16 + r;
        if (row < N) {
            float s = (MODE == 0) ? aux[row] : 0.f;
#pragma unroll
            for (int j = 0; j < OPL; ++j) {
                float a = acc2[r][j].x + acc2[r][j].y;
                float o;
                if (MODE == 0) o = a * s;
                else           o = fmaxf(a + bv[j], 0.f);
                G[(size_t)row * COUT + j * 64 + lane] = o;
            }
        }
    }
}

// ---------------------------------------------------------------------------
// SpMM: acc = G[v] + sum_{e in row v} G[col[e]];  s = dinv[v]
//   r = acc*s; if HAS_BIAS r += b; if RELU r=max(r,0); if PRESCALE r *= s
// One wave per node; lane covers 2 channels (COUT=128) or 1 (COUT=64).
// ---------------------------------------------------------------------------
template <int COUT, bool RELU, bool HAS_BIAS, bool PRESCALE>
__global__ __launch_bounds__(256) void k_spmm(const float* __restrict__ G,
                                              const int* __restrict__ rp,
                                              const int* __restrict__ col,
                                              const float* __restrict__ dinv,
                                              const float* __restrict__ bias,
                                              float* __restrict__ Y, int N) {
    int wid = threadIdx.x >> 6, lane = threadIdx.x & 63;
    int v = blockIdx.x * 4 + wid;
    if (v >= N) return;

    if (COUT == 128) {
        float2 acc = *(const float2*)(G + (size_t)v * 128 + 2 * lane);
        int e = rp[v], end = rp[v + 1];
        for (; e + 4 <= end; e += 4) {
            int u0 = col[e], u1 = col[e + 1], u2 = col[e + 2], u3 = col[e + 3];
            float2 a0 = *(const float2*)(G + (size_t)u0 * 128 + 2 * lane);
            float2 a1 = *(const float2*)(G + (size_t)u1 * 128 + 2 * lane);
            float2 a2 = *(const float2*)(G + (size_t)u2 * 128 + 2 * lane);
            float2 a3 = *(const float2*)(G + (size_t)u3 * 128 + 2 * lane);
            acc.x += a0.x + a1.x + a2.x + a3.x;
            acc.y += a0.y + a1.y + a2.y + a3.y;
        }
        for (; e < end; ++e) {
            int u = col[e];
            float2 a = *(const float2*)(G + (size_t)u * 128 + 2 * lane);
            acc.x += a.x; acc.y += a.y;
        }
        float s = dinv[v];
        float rx = acc.x * s;
        float ry = acc.y * s;
        if (HAS_BIAS) { rx += bias[2 * lane]; ry += bias[2 * lane + 1]; }
        if (RELU) { rx = fmaxf(rx, 0.f); ry = fmaxf(ry, 0.f); }
        if (PRESCALE) { rx *= s; ry *= s; }
        float2 out; out.x = rx; out.y = ry;
        *(float2*)(Y + (size_t)v * 128 + 2 * lane) = out;
    } else {  // COUT == 64
        float acc = G[(size_t)v * 64 + lane];
        int e = rp[v], end = rp[v + 1];
        for (; e + 4 <= end; e += 4) {
            int u0 = col[e], u1 = col[e + 1], u2 = col[e + 2], u3 = col[e + 3];
            float a0 = G[(size_t)u0 * 64 + lane];
            float a1 = G[(size_t)u1 * 64 + lane];
            float a2 = G[(size_t)u2 * 64 + lane];
            float a3 = G[(size_t)u3 * 64 + lane];
            acc += a0 + a1 + a2 + a3;
        }
        for (; e < end; ++e) acc += G[(size_t)col[e] * 64 + lane];
        float s = dinv[v];
        float r = acc * s;
        if (HAS_BIAS) r += bias[lane];
        if (RELU) r = fmaxf(r, 0.f);
        if (PRESCALE) r *= s;
        Y[(size_t)v * 64 + lane] = r;
    }
}

// ---------------------------------------------------------------------------
extern "C" void kernel_launch(void* const* d_in, const int* in_sizes, int n_in,
                              void* d_out, int out_size, void* d_ws, size_t ws_size,
                              hipStream_t stream) {
    const float* x  = (const float*)d_in[0];
    const void*  ei = d_in[1];
    const float* W1 = (const float*)d_in[2];
    const float* b1 = (const float*)d_in[3];
    const float* W2 = (const float*)d_in[4];
    const float* b2 = (const float*)d_in[5];
    const float* W3 = (const float*)d_in[6];
    const float* b3 = (const float*)d_in[7];
    const float* W4 = (const float*)d_in[8];
    const float* b4 = (const float*)d_in[9];

    const int N = in_sizes[0] / 128;   // 100000
    const int E = in_sizes[1] / 2;     // 1600000

    // workspace carve-up (256B aligned)
    size_t off = 0;
    auto alloc = [&](size_t bytes) -> void* {
        void* p = (char*)d_ws + off;
        off += (bytes + 255) & ~(size_t)255;
        return p;
    };
    u32*   flag    = (u32*)  alloc(4);
    int*   src32   = (int*)  alloc((size_t)E * 4);
    int*   dst32   = (int*)  alloc((size_t)E * 4);
    u32*   deg     = (u32*)  alloc((size_t)N * 4);
    float* dinv    = (float*)alloc((size_t)N * 4);
    int*   row_ptr = (int*)  alloc((size_t)(N + 1) * 4);
    u32*   cnt     = (u32*)  alloc((size_t)N * 4);
    u32*   partial = (u32*)  alloc(256 * 4);
    int*   col     = (int*)  alloc((size_t)E * 4);
    float* Wt      = (float*)alloc(128 * 128 * 4);
    float* A       = (float*)alloc((size_t)N * 128 * 4);
    float* B       = (float*)alloc((size_t)N * 128 * 4);
    float* Z       = (float*)d_out;    // zh bottleneck (N x 64) reuses d_out

    const int n2 = 2 * E;
    const int NB = (N + 1023) / 1024;

    // graph preprocessing
    k_detect<<<1, 256, 0, stream>>>((const int*)ei, n2, flag);
    k_convert<<<(n2 + 255) / 256, 256, 0, stream>>>(ei, n2, flag, src32);  // [0..E)=src, [E..2E)=dst
    int* dstp = src32 + E;
    k_init<<<(N + 255) / 256, 256, 0, stream>>>(deg, cnt, N);
    k_count<<<(E + 255) / 256, 256, 0, stream>>>(dstp, deg, E);
    k_dinv<<<(N + 255) / 256, 256, 0, stream>>>(deg, dinv, N);
    k_scan_a<<<NB, 256, 0, stream>>>(deg, partial, N);
    k_scan_b<<<1, 128, 0, stream>>>(partial, NB, row_ptr, N);
    k_scan_c<<<NB, 256, 0, stream>>>(deg, partial, row_ptr, N);
    k_fill<<<(E + 255) / 256, 256, 0, stream>>>(src32, dstp, row_ptr, cnt, col, E);
    (void)dst32;

    const int gG = (N + 63) / 64;    // gemm grid
    const int gS = (N + 3) / 4;      // spmm grid

    // Layer 1: h1 = relu(agg(x@W1ᵀ)) : transform -> aggregate(128)
    k_transpose<128, 128><<<(128 * 128 + 255) / 256, 256, 0, stream>>>(W1, Wt);
    k_gemm<128, 128, 0><<<gG, 256, 0, stream>>>(x, Wt, dinv, A, N);
    k_spmm<128, true, true, false><<<gS, 256, 0, stream>>>(A, row_ptr, col, dinv, b1, B, N);

    // Layer 2: zh = dinv * (agg(h1@W2ᵀ) + b2) : transform -> aggregate(64), prescaled out
    k_transpose<128, 64><<<(128 * 64 + 255) / 256, 256, 0, stream>>>(W2, Wt);
    k_gemm<128, 64, 0><<<gG, 256, 0, stream>>>(B, Wt, dinv, A, N);
    k_spmm<64, false, true, true><<<gS, 256, 0, stream>>>(A, row_ptr, col, dinv, b2, Z, N);

    // Layer 3 (reordered): aggregate(64) FIRST, then GEMM 64->128 with bias+relu
    k_spmm<64, false, false, false><<<gS, 256, 0, stream>>>(Z, row_ptr, col, dinv, b2, B, N);
    k_transpose<64, 128><<<(64 * 128 + 255) / 256, 256, 0, stream>>>(W3, Wt);
    k_gemm<64, 128, 1><<<gG, 256, 0, stream>>>(B, Wt, b3, A, N);  // A = h3

    // Layer 4: transform -> aggregate(128)
    k_transpose<128, 128><<<(128 * 128 + 255) / 256, 256, 0, stream>>>(W4, Wt);
    k_gemm<128, 128, 0><<<gG, 256, 0, stream>>>(A, Wt, dinv, B, N);
    k_spmm<128, false, true, false><<<gS, 256, 0, stream>>>(B, row_ptr, col, dinv, b4, (float*)d_out, N);
}

// Round 4
// 801.401 us; speedup vs baseline: 1.5427x; 1.0379x over previous
//
#include <hip/hip_runtime.h>

typedef unsigned int u32;
using v2f = __attribute__((ext_vector_type(2))) float;

// ---------------------------------------------------------------------------
// Edge-index dtype detection: if the buffer is int64 (little-endian, values
// < 2^31), every odd int32 slot is zero. If int32, odd slots are random
// node indices (P(all zero) ~ 0).
// ---------------------------------------------------------------------------
__global__ void k_detect(const int* __restrict__ p, int n_int32, u32* __restrict__ flag) {
    __shared__ int s[256];
    int tid = threadIdx.x;
    int acc = 0;
    int limit = n_int32 < 2048 ? n_int32 : 2048;
    for (int i = 1 + 2 * tid; i < limit; i += 512) acc |= p[i];
    s[tid] = acc;
    __syncthreads();
    for (int o = 128; o > 0; o >>= 1) {
        if (tid < o) s[tid] |= s[tid + o];
        __syncthreads();
    }
    if (tid == 0) *flag = (s[0] == 0) ? 1u : 0u;
}

__global__ void k_convert(const void* __restrict__ p, int n, const u32* __restrict__ flag,
                          int* __restrict__ out) {
    int i = blockIdx.x * blockDim.x + threadIdx.x;
    if (i >= n) return;
    if (*flag) out[i] = (int)((const long long*)p)[i];
    else       out[i] = ((const int*)p)[i];
}

// ---------------------------------------------------------------------------
// Degree / dinv / CSR build
// ---------------------------------------------------------------------------
__global__ void k_init(u32* __restrict__ deg, u32* __restrict__ cnt, int N) {
    int i = blockIdx.x * blockDim.x + threadIdx.x;
    if (i < N) { deg[i] = 1u; cnt[i] = 0u; }  // deg starts at 1 (self-loop)
}

// XCD-range-partitioned degree count: blocks with (bid&7)==x handle dst range
// [N*x/8, N*(x+1)/8). Keeps the atomic working set (~50KB) resident in one
// XCD's L2 instead of bouncing lines between non-coherent L2s.
__global__ __launch_bounds__(256) void k_count(const int* __restrict__ dst,
                                               u32* __restrict__ deg, int E, int N) {
    int xcd = blockIdx.x & 7;
    int sub = blockIdx.x >> 3;
    int nsub = gridDim.x >> 3;
    int lo = (int)((long long)N * xcd >> 3);
    int hi = (int)((long long)N * (xcd + 1) >> 3);
    for (int e = sub * 256 + threadIdx.x; e < E; e += nsub * 256) {
        int d = dst[e];
        if (d >= lo && d < hi) atomicAdd(&deg[d], 1u);
    }
}

__global__ void k_dinv(const u32* __restrict__ deg, float* __restrict__ dinv, int N) {
    int i = blockIdx.x * blockDim.x + threadIdx.x;
    if (i < N) dinv[i] = rsqrtf((float)deg[i]);
}

// 3-phase exclusive scan of (deg[v]-1) -> row_ptr. Chunk = 1024 elems/block.
__global__ void k_scan_a(const u32* __restrict__ deg, u32* __restrict__ partial, int N) {
    __shared__ u32 s[256];
    int tid = threadIdx.x;
    int base = blockIdx.x * 1024 + tid * 4;
    u32 sum = 0;
#pragma unroll
    for (int j = 0; j < 4; ++j) {
        int v = base + j;
        sum += (v < N) ? (deg[v] - 1u) : 0u;
    }
    s[tid] = sum;
    __syncthreads();
    for (int o = 128; o > 0; o >>= 1) {
        if (tid < o) s[tid] += s[tid + o];
        __syncthreads();
    }
    if (tid == 0) partial[blockIdx.x] = s[0];
}

__global__ void k_scan_b(u32* __restrict__ partial, int NB, int* __restrict__ row_ptr, int N) {
    __shared__ u32 s[128];
    int tid = threadIdx.x;  // 128 threads
    u32 v = (tid < NB) ? partial[tid] : 0u;
    s[tid] = v;
    __syncthreads();
    for (int off = 1; off < 128; off <<= 1) {
        u32 t = (tid >= off) ? s[tid - off] : 0u;
        __syncthreads();
        s[tid] += t;
        __syncthreads();
    }
    if (tid < NB) partial[tid] = s[tid] - v;    // exclusive
    if (tid == 127) row_ptr[N] = (int)s[127];   // total = E
}

__global__ void k_scan_c(const u32* __restrict__ deg, const u32* __restrict__ partial,
                         int* __restrict__ row_ptr, int N) {
    __shared__ u32 s[256];
    int tid = threadIdx.x;
    int base = blockIdx.x * 1024 + tid * 4;
    u32 vals[4];
    u32 sum = 0;
#pragma unroll
    for (int j = 0; j < 4; ++j) {
        int v = base + j;
        vals[j] = (v < N) ? (deg[v] - 1u) : 0u;
        sum += vals[j];
    }
    s[tid] = sum;
    __syncthreads();
    for (int off = 1; off < 256; off <<= 1) {
        u32 t = (tid >= off) ? s[tid - off] : 0u;
        __syncthreads();
        s[tid] += t;
        __syncthreads();
    }
    u32 run = s[tid] - sum + partial[blockIdx.x];
#pragma unroll
    for (int j = 0; j < 4; ++j) {
        int v = base + j;
        if (v < N) row_ptr[v] = (int)run;
        run += vals[j];
    }
}

// XCD-range-partitioned CSR fill: same partitioning as k_count. Each XCD's
// col write window is ~800KB -> L2-resident -> full-line evictions instead of
// 1.6M partial-line HBM writes.
__global__ __launch_bounds__(256) void k_fill(const int* __restrict__ src,
                                              const int* __restrict__ dst,
                                              const int* __restrict__ row_ptr,
                                              u32* __restrict__ cnt,
                                              int* __restrict__ col, int E, int N) {
    int xcd = blockIdx.x & 7;
    int sub = blockIdx.x >> 3;
    int nsub = gridDim.x >> 3;
    int lo = (int)((long long)N * xcd >> 3);
    int hi = (int)((long long)N * (xcd + 1) >> 3);
    for (int e = sub * 256 + threadIdx.x; e < E; e += nsub * 256) {
        int d = dst[e];
        if (d >= lo && d < hi) {
            int pos = row_ptr[d] + (int)atomicAdd(&cnt[d], 1u);
            col[pos] = src[e];
        }
    }
}

// ---------------------------------------------------------------------------
// Weight transpose: Wt[k*COUT + o] = W[o*CIN + k]
// ---------------------------------------------------------------------------
template <int CIN, int COUT>
__global__ void k_transpose(const float* __restrict__ W, float* __restrict__ Wt) {
    int i = blockIdx.x * blockDim.x + threadIdx.x;
    if (i >= CIN * COUT) return;
    int k = i / COUT, o = i % COUT;
    Wt[i] = W[o * CIN + k];
}

// ---------------------------------------------------------------------------
// GEMM: out[row][o] = epilogue( sum_k X[row][k] * W[o][k] )
//   MODE 0: out = acc * dinv[row]            (aux = dinv)
//   MODE 1: out = relu(acc + bias[o])        (aux = bias)
// Block = 256 thr (4 waves) = 64 rows. K chunks of KC<=64 staged in LDS.
// ---------------------------------------------------------------------------
template <int CIN, int COUT, int MODE>
__global__ __launch_bounds__(256) void k_gemm(const float* __restrict__ X,
                                              const float* __restrict__ Wt,
                                              const float* __restrict__ aux,
                                              float* __restrict__ G, int N) {
    constexpr int OPL = COUT / 64;           // outputs per lane (1 or 2)
    constexpr int KC = (CIN < 64) ? CIN : 64;
    constexpr int XPITCH = KC + 4;           // pad: break stage-write conflicts
    __shared__ __align__(16) float sW[KC * COUT];
    __shared__ __align__(16) float sX[64 * XPITCH];

    int tid = threadIdx.x, wid = tid >> 6, lane = tid & 63;
    int rowbase = blockIdx.x * 64;

    v2f acc2[16][OPL];
#pragma unroll
    for (int r = 0; r < 16; ++r)
#pragma unroll
        for (int j = 0; j < OPL; ++j) acc2[r][j] = (v2f){0.f, 0.f};

    for (int k0 = 0; k0 < CIN; k0 += KC) {
        __syncthreads();  // protect previous chunk's reads before overwrite
        // stage W chunk: contiguous region of Wt
        for (int i = 4 * tid; i < KC * COUT; i += 1024)
            *(float4*)&sW[i] = *(const float4*)&Wt[(size_t)k0 * COUT + i];
        // stage X tile: 64 rows x KC cols; 4 threads per row, 16 floats each
        {
            int r = tid >> 2, p = tid & 3;
            int row = rowbase + r;
            if (row >= N) row = N - 1;       // clamp (stores guarded later)
            const float4* xp = (const float4*)(X + (size_t)row * CIN + k0 + p * 16);
            float* sp = &sX[r * XPITCH + p * 16];
#pragma unroll
            for (int j = 0; j < 4; ++j) *(float4*)(sp + 4 * j) = xp[j];
        }
        __syncthreads();

        const float* sXw = &sX[wid * 16 * XPITCH];
#pragma unroll 4
        for (int k = 0; k < KC; k += 4) {
            v2f w01[OPL], w23[OPL];
#pragma unroll
            for (int j = 0; j < OPL; ++j) {
                w01[j] = (v2f){sW[(k + 0) * COUT + j * 64 + lane],
                               sW[(k + 1) * COUT + j * 64 + lane]};
                w23[j] = (v2f){sW[(k + 2) * COUT + j * 64 + lane],
                               sW[(k + 3) * COUT + j * 64 + lane]};
            }
#pragma unroll
            for (int r = 0; r < 16; ++r) {
                float4 xv = *(const float4*)&sXw[r * XPITCH + k];
                v2f x01 = (v2f){xv.x, xv.y};
                v2f x23 = (v2f){xv.z, xv.w};
#pragma unroll
                for (int j = 0; j < OPL; ++j) {
                    acc2[r][j] += x01 * w01[j];
                    acc2[r][j] += x23 * w23[j];
                }
            }
        }
    }

    // epilogue
    float bv[OPL];
    if (MODE == 1) {
#pragma unroll
        for (int j = 0; j < OPL; ++j) bv[j] = aux[j * 64 + lane];
    }
#pragma unroll
    for (int r = 0; r < 16; ++r) {
        int row = rowbase + wid * 16 + r;
        if (row < N) {
            float s = (MODE == 0) ? aux[row] : 0.f;
#pragma unroll
            for (int j = 0; j < OPL; ++j) {
                float a = acc2[r][j].x + acc2[r][j].y;
                float o;
                if (MODE == 0) o = a * s;
                else           o = fmaxf(a + bv[j], 0.f);
                G[(size_t)row * COUT + j * 64 + lane] = o;
            }
        }
    }
}

// ---------------------------------------------------------------------------
// SpMM: acc = G[v] + sum_{e in row v} G[col[e]];  s = dinv[v]
//   r = acc*s; if HAS_BIAS r += b; if RELU r=max(r,0); if PRESCALE r *= s
// One wave per node. 8 gathers kept in flight (latency/MLP-bound loop).
// ---------------------------------------------------------------------------
template <int COUT, bool RELU, bool HAS_BIAS, bool PRESCALE>
__global__ __launch_bounds__(256) void k_spmm(const float* __restrict__ G,
                                              const int* __restrict__ rp,
                                              const int* __restrict__ col,
                                              const float* __restrict__ dinv,
                                              const float* __restrict__ bias,
                                              float* __restrict__ Y, int N) {
    int wid = threadIdx.x >> 6, lane = threadIdx.x & 63;
    int v = blockIdx.x * 4 + wid;
    if (v >= N) return;

    if (COUT == 128) {
        const float2* Gp = (const float2*)G;
        float2 acc = Gp[(size_t)v * 64 + lane];
        int e = rp[v], end = rp[v + 1];
        for (; e + 8 <= end; e += 8) {
            int u[8];
#pragma unroll
            for (int j = 0; j < 8; ++j) u[j] = col[e + j];
            float2 a[8];
#pragma unroll
            for (int j = 0; j < 8; ++j) a[j] = Gp[(size_t)u[j] * 64 + lane];
            float sx = ((a[0].x + a[1].x) + (a[2].x + a[3].x)) +
                       ((a[4].x + a[5].x) + (a[6].x + a[7].x));
            float sy = ((a[0].y + a[1].y) + (a[2].y + a[3].y)) +
                       ((a[4].y + a[5].y) + (a[6].y + a[7].y));
            acc.x += sx; acc.y += sy;
        }
        for (; e < end; ++e) {
            int u = col[e];
            float2 a = Gp[(size_t)u * 64 + lane];
            acc.x += a.x; acc.y += a.y;
        }
        float s = dinv[v];
        float rx = acc.x * s;
        float ry = acc.y * s;
        if (HAS_BIAS) { rx += bias[2 * lane]; ry += bias[2 * lane + 1]; }
        if (RELU) { rx = fmaxf(rx, 0.f); ry = fmaxf(ry, 0.f); }
        if (PRESCALE) { rx *= s; ry *= s; }
        float2 out; out.x = rx; out.y = ry;
        *(float2*)(Y + (size_t)v * 128 + 2 * lane) = out;
    } else {  // COUT == 64
        float acc = G[(size_t)v * 64 + lane];
        int e = rp[v], end = rp[v + 1];
        for (; e + 8 <= end; e += 8) {
            int u[8];
#pragma unroll
            for (int j = 0; j < 8; ++j) u[j] = col[e + j];
            float a[8];
#pragma unroll
            for (int j = 0; j < 8; ++j) a[j] = G[(size_t)u[j] * 64 + lane];
            acc += ((a[0] + a[1]) + (a[2] + a[3])) + ((a[4] + a[5]) + (a[6] + a[7]));
        }
        for (; e < end; ++e) acc += G[(size_t)col[e] * 64 + lane];
        float s = dinv[v];
        float r = acc * s;
        if (HAS_BIAS) r += bias[lane];
        if (RELU) r = fmaxf(r, 0.f);
        if (PRESCALE) r *= s;
        Y[(size_t)v * 64 + lane] = r;
    }
}

// ---------------------------------------------------------------------------
extern "C" void kernel_launch(void* const* d_in, const int* in_sizes, int n_in,
                              void* d_out, int out_size, void* d_ws, size_t ws_size,
                              hipStream_t stream) {
    const float* x  = (const float*)d_in[0];
    const void*  ei = d_in[1];
    const float* W1 = (const float*)d_in[2];
    const float* b1 = (const float*)d_in[3];
    const float* W2 = (const float*)d_in[4];
    const float* b2 = (const float*)d_in[5];
    const float* W3 = (const float*)d_in[6];
    const float* b3 = (const float*)d_in[7];
    const float* W4 = (const float*)d_in[8];
    const float* b4 = (const float*)d_in[9];

    const int N = in_sizes[0] / 128;   // 100000
    const int E = in_sizes[1] / 2;     // 1600000

    // workspace carve-up (256B aligned)
    size_t off = 0;
    auto alloc = [&](size_t bytes) -> void* {
        void* p = (char*)d_ws + off;
        off += (bytes + 255) & ~(size_t)255;
        return p;
    };
    u32*   flag    = (u32*)  alloc(4);
    int*   src32   = (int*)  alloc((size_t)E * 4);
    int*   dst32   = (int*)  alloc((size_t)E * 4);
    u32*   deg     = (u32*)  alloc((size_t)N * 4);
    float* dinv    = (float*)alloc((size_t)N * 4);
    int*   row_ptr = (int*)  alloc((size_t)(N + 1) * 4);
    u32*   cnt     = (u32*)  alloc((size_t)N * 4);
    u32*   partial = (u32*)  alloc(256 * 4);
    int*   col     = (int*)  alloc((size_t)E * 4);
    float* Wt      = (float*)alloc(128 * 128 * 4);
    float* A       = (float*)alloc((size_t)N * 128 * 4);
    float* B       = (float*)alloc((size_t)N * 128 * 4);
    float* Z       = (float*)d_out;    // zh bottleneck (N x 64) reuses d_out

    const int n2 = 2 * E;
    const int NB = (N + 1023) / 1024;

    // graph preprocessing
    k_detect<<<1, 256, 0, stream>>>((const int*)ei, n2, flag);
    k_convert<<<(n2 + 255) / 256, 256, 0, stream>>>(ei, n2, flag, src32);  // [0..E)=src, [E..2E)=dst
    int* dstp = src32 + E;
    k_init<<<(N + 255) / 256, 256, 0, stream>>>(deg, cnt, N);
    k_count<<<1024, 256, 0, stream>>>(dstp, deg, E, N);
    k_dinv<<<(N + 255) / 256, 256, 0, stream>>>(deg, dinv, N);
    k_scan_a<<<NB, 256, 0, stream>>>(deg, partial, N);
    k_scan_b<<<1, 128, 0, stream>>>(partial, NB, row_ptr, N);
    k_scan_c<<<NB, 256, 0, stream>>>(deg, partial, row_ptr, N);
    k_fill<<<1024, 256, 0, stream>>>(src32, dstp, row_ptr, cnt, col, E, N);
    (void)dst32;

    const int gG = (N + 63) / 64;    // gemm grid
    const int gS = (N + 3) / 4;      // spmm grid

    // Layer 1: h1 = relu(agg(x@W1ᵀ)) : transform -> aggregate(128)
    k_transpose<128, 128><<<(128 * 128 + 255) / 256, 256, 0, stream>>>(W1, Wt);
    k_gemm<128, 128, 0><<<gG, 256, 0, stream>>>(x, Wt, dinv, A, N);
    k_spmm<128, true, true, false><<<gS, 256, 0, stream>>>(A, row_ptr, col, dinv, b1, B, N);

    // Layer 2: zh = dinv * (agg(h1@W2ᵀ) + b2) : transform -> aggregate(64), prescaled out
    k_transpose<128, 64><<<(128 * 64 + 255) / 256, 256, 0, stream>>>(W2, Wt);
    k_gemm<128, 64, 0><<<gG, 256, 0, stream>>>(B, Wt, dinv, A, N);
    k_spmm<64, false, true, true><<<gS, 256, 0, stream>>>(A, row_ptr, col, dinv, b2, Z, N);

    // Layer 3 (reordered): aggregate(64) FIRST, then GEMM 64->128 with bias+relu
    k_spmm<64, false, false, false><<<gS, 256, 0, stream>>>(Z, row_ptr, col, dinv, b2, B, N);
    k_transpose<64, 128><<<(64 * 128 + 255) / 256, 256, 0, stream>>>(W3, Wt);
    k_gemm<64, 128, 1><<<gG, 256, 0, stream>>>(B, Wt, b3, A, N);  // A = h3

    // Layer 4: transform -> aggregate(128)
    k_transpose<128, 128><<<(128 * 128 + 255) / 256, 256, 0, stream>>>(W4, Wt);
    k_gemm<128, 128, 0><<<gG, 256, 0, stream>>>(A, Wt, dinv, B, N);
    k_spmm<128, false, true, false><<<gS, 256, 0, stream>>>(B, row_ptr, col, dinv, b4, (float*)d_out, N);
}

// Round 5
// 672.799 us; speedup vs baseline: 1.8375x; 1.1911x over previous
//
#include <hip/hip_runtime.h>

typedef unsigned int u32;
typedef unsigned short u16;
using v2f = __attribute__((ext_vector_type(2))) float;

// bf16 helpers: round-to-nearest-even pack, cheap unpack
__device__ inline u16 f2bf_rne(float f) {
    u32 b = __float_as_uint(f);
    return (u16)((b + 0x7FFFu + ((b >> 16) & 1u)) >> 16);
}
__device__ inline float bf2f(u16 h) { return __uint_as_float((u32)h << 16); }
__device__ inline float2 bfpair(u32 q) {
    float2 f;
    f.x = __uint_as_float(q << 16);
    f.y = __uint_as_float(q & 0xFFFF0000u);
    return f;
}

// ---------------------------------------------------------------------------
// Edge-index dtype detection (int64 vs int32 buffer)
// ---------------------------------------------------------------------------
__global__ void k_detect(const int* __restrict__ p, int n_int32, u32* __restrict__ flag) {
    __shared__ int s[256];
    int tid = threadIdx.x;
    int acc = 0;
    int limit = n_int32 < 2048 ? n_int32 : 2048;
    for (int i = 1 + 2 * tid; i < limit; i += 512) acc |= p[i];
    s[tid] = acc;
    __syncthreads();
    for (int o = 128; o > 0; o >>= 1) {
        if (tid < o) s[tid] |= s[tid + o];
        __syncthreads();
    }
    if (tid == 0) *flag = (s[0] == 0) ? 1u : 0u;
}

__global__ void k_convert(const void* __restrict__ p, int n, const u32* __restrict__ flag,
                          int* __restrict__ out) {
    int i = blockIdx.x * blockDim.x + threadIdx.x;
    if (i >= n) return;
    if (*flag) out[i] = (int)((const long long*)p)[i];
    else       out[i] = ((const int*)p)[i];
}

// ---------------------------------------------------------------------------
// Degree / dinv / CSR build
// ---------------------------------------------------------------------------
__global__ void k_init(u32* __restrict__ deg, u32* __restrict__ cnt, int N) {
    int i = blockIdx.x * blockDim.x + threadIdx.x;
    if (i < N) { deg[i] = 1u; cnt[i] = 0u; }  // deg starts at 1 (self-loop)
}

// XCD-range-partitioned degree count (keeps atomic lines in one XCD's L2)
__global__ __launch_bounds__(256) void k_count(const int* __restrict__ dst,
                                               u32* __restrict__ deg, int E, int N) {
    int xcd = blockIdx.x & 7;
    int sub = blockIdx.x >> 3;
    int nsub = gridDim.x >> 3;
    int lo = (int)((long long)N * xcd >> 3);
    int hi = (int)((long long)N * (xcd + 1) >> 3);
    for (int e = sub * 256 + threadIdx.x; e < E; e += nsub * 256) {
        int d = dst[e];
        if (d >= lo && d < hi) atomicAdd(&deg[d], 1u);
    }
}

__global__ void k_dinv(const u32* __restrict__ deg, float* __restrict__ dinv, int N) {
    int i = blockIdx.x * blockDim.x + threadIdx.x;
    if (i < N) dinv[i] = rsqrtf((float)deg[i]);
}

// 3-phase exclusive scan of (deg[v]-1) -> row_ptr
__global__ void k_scan_a(const u32* __restrict__ deg, u32* __restrict__ partial, int N) {
    __shared__ u32 s[256];
    int tid = threadIdx.x;
    int base = blockIdx.x * 1024 + tid * 4;
    u32 sum = 0;
#pragma unroll
    for (int j = 0; j < 4; ++j) {
        int v = base + j;
        sum += (v < N) ? (deg[v] - 1u) : 0u;
    }
    s[tid] = sum;
    __syncthreads();
    for (int o = 128; o > 0; o >>= 1) {
        if (tid < o) s[tid] += s[tid + o];
        __syncthreads();
    }
    if (tid == 0) partial[blockIdx.x] = s[0];
}

__global__ void k_scan_b(u32* __restrict__ partial, int NB, int* __restrict__ row_ptr, int N) {
    __shared__ u32 s[128];
    int tid = threadIdx.x;
    u32 v = (tid < NB) ? partial[tid] : 0u;
    s[tid] = v;
    __syncthreads();
    for (int off = 1; off < 128; off <<= 1) {
        u32 t = (tid >= off) ? s[tid - off] : 0u;
        __syncthreads();
        s[tid] += t;
        __syncthreads();
    }
    if (tid < NB) partial[tid] = s[tid] - v;
    if (tid == 127) row_ptr[N] = (int)s[127];
}

__global__ void k_scan_c(const u32* __restrict__ deg, const u32* __restrict__ partial,
                         int* __restrict__ row_ptr, int N) {
    __shared__ u32 s[256];
    int tid = threadIdx.x;
    int base = blockIdx.x * 1024 + tid * 4;
    u32 vals[4];
    u32 sum = 0;
#pragma unroll
    for (int j = 0; j < 4; ++j) {
        int v = base + j;
        vals[j] = (v < N) ? (deg[v] - 1u) : 0u;
        sum += vals[j];
    }
    s[tid] = sum;
    __syncthreads();
    for (int off = 1; off < 256; off <<= 1) {
        u32 t = (tid >= off) ? s[tid - off] : 0u;
        __syncthreads();
        s[tid] += t;
        __syncthreads();
    }
    u32 run = s[tid] - sum + partial[blockIdx.x];
#pragma unroll
    for (int j = 0; j < 4; ++j) {
        int v = base + j;
        if (v < N) row_ptr[v] = (int)run;
        run += vals[j];
    }
}

// XCD-range-partitioned CSR fill
__global__ __launch_bounds__(256) void k_fill(const int* __restrict__ src,
                                              const int* __restrict__ dst,
                                              const int* __restrict__ row_ptr,
                                              u32* __restrict__ cnt,
                                              int* __restrict__ col, int E, int N) {
    int xcd = blockIdx.x & 7;
    int sub = blockIdx.x >> 3;
    int nsub = gridDim.x >> 3;
    int lo = (int)((long long)N * xcd >> 3);
    int hi = (int)((long long)N * (xcd + 1) >> 3);
    for (int e = sub * 256 + threadIdx.x; e < E; e += nsub * 256) {
        int d = dst[e];
        if (d >= lo && d < hi) {
            int pos = row_ptr[d] + (int)atomicAdd(&cnt[d], 1u);
            col[pos] = src[e];
        }
    }
}

// ---------------------------------------------------------------------------
// GEMM v4: out[row][o] = epilogue( sum_k X[row][k] * W[o][k] )
//   MODE 0: out = acc * dinv[row]   (aux = dinv)
//   MODE 1: out = relu(acc + bias)  (aux = bias)
// W read directly from global (native [o][k] layout, L2-resident) into
// per-lane registers; X staged in LDS, consumed as wave-uniform b128
// broadcasts. Lane covers channel(s) o = 2*lane+j (COUT=128) or lane (64).
// Block = 256 thr = 4 waves; 64 rows/block; 16 rows/wave.
// ---------------------------------------------------------------------------
template <int CIN, int COUT, int MODE, bool OUT_BF16>
__global__ __launch_bounds__(256, 3) void k_gemm(const float* __restrict__ X,
                                                 const float* __restrict__ W,
                                                 const float* __restrict__ aux,
                                                 void* __restrict__ Gout, int N) {
    constexpr int OPL = COUT / 64;   // 2 -> o = 2*lane+j ; 1 -> o = lane
    constexpr int KC = 64;           // k-chunk staged in LDS
    constexpr int PITCH = 68;        // 272B rows: 16B-aligned, conflict-padded
    __shared__ __align__(16) float sX[64 * PITCH];

    int tid = threadIdx.x, wid = tid >> 6, lane = tid & 63;
    int rowbase = blockIdx.x * 64;
    int r0w = wid * 16;

    v2f acc[16][OPL];
#pragma unroll
    for (int r = 0; r < 16; ++r)
#pragma unroll
        for (int j = 0; j < OPL; ++j) acc[r][j] = (v2f){0.f, 0.f};

    for (int k0 = 0; k0 < CIN; k0 += KC) {
        __syncthreads();
        // stage X tile: 64 rows x KC cols; 4 threads per row x 16 floats
        {
            int r = tid >> 2, p = tid & 3;
            int row = rowbase + r;
            if (row >= N) row = N - 1;   // clamp (stores guarded later)
            const float4* xp = (const float4*)(X + (size_t)row * CIN + k0 + p * 16);
            float4* sp = (float4*)&sX[r * PITCH + p * 16];
            sp[0] = xp[0]; sp[1] = xp[1]; sp[2] = xp[2]; sp[3] = xp[3];
        }
        __syncthreads();

        for (int kr = 0; kr < KC; kr += 32) {
            // W chunk -> registers (global, L2-hot): OPL x 8 float4
            float4 wf[OPL][8];
#pragma unroll
            for (int j = 0; j < OPL; ++j) {
                int o = (OPL == 2) ? (2 * lane + j) : lane;
                const float4* wp = (const float4*)(W + (size_t)o * CIN + k0 + kr);
#pragma unroll
                for (int q = 0; q < 8; ++q) wf[j][q] = wp[q];
            }
#pragma unroll
            for (int r = 0; r < 16; ++r) {
                const float* xb = &sX[(r0w + r) * PITCH + kr];
#pragma unroll
                for (int q = 0; q < 8; ++q) {
                    float4 xv = *(const float4*)(xb + 4 * q);
                    v2f x01 = (v2f){xv.x, xv.y};
                    v2f x23 = (v2f){xv.z, xv.w};
#pragma unroll
                    for (int j = 0; j < OPL; ++j) {
                        acc[r][j] += x01 * (v2f){wf[j][q].x, wf[j][q].y};
                        acc[r][j] += x23 * (v2f){wf[j][q].z, wf[j][q].w};
                    }
                }
            }
        }
    }

    // epilogue
    float bv[OPL];
    if (MODE == 1) {
#pragma unroll
        for (int j = 0; j < OPL; ++j)
            bv[j] = aux[(OPL == 2) ? (2 * lane + j) : lane];
    }
#pragma unroll
    for (int r = 0; r < 16; ++r) {
        int row = rowbase + r0w + r;
        if (row < N) {
            float s = (MODE == 0) ? aux[row] : 0.f;
            float vv[OPL];
#pragma unroll
            for (int j = 0; j < OPL; ++j) {
                float a = acc[r][j].x + acc[r][j].y;
                vv[j] = (MODE == 0) ? a * s : fmaxf(a + bv[j], 0.f);
            }
            if (OUT_BF16) {
                if (OPL == 2) {
                    u32 pk = (u32)f2bf_rne(vv[0]) | ((u32)f2bf_rne(vv[1]) << 16);
                    ((u32*)Gout)[row * 64 + lane] = pk;
                } else {
                    ((u16*)Gout)[row * 64 + lane] = f2bf_rne(vv[0]);
                }
            } else {
                if (OPL == 2) {
                    float2 o2; o2.x = vv[0]; o2.y = vv[1];
                    *(float2*)((float*)Gout + (size_t)row * 128 + 2 * lane) = o2;
                } else {
                    ((float*)Gout)[row * 64 + lane] = vv[0];
                }
            }
        }
    }
}

// ---------------------------------------------------------------------------
// SpMM-128 (bf16 in, f32 out): acc = G[v] + sum G[col[e]]; r = acc*dinv[v]
// Lane holds channel pair (2*lane, 2*lane+1) packed in one u32.
// ---------------------------------------------------------------------------
template <bool RELU, bool HAS_BIAS>
__global__ __launch_bounds__(256) void k_spmm128(const u32* __restrict__ Gq,
                                                 const int* __restrict__ rp,
                                                 const int* __restrict__ col,
                                                 const float* __restrict__ dinv,
                                                 const float* __restrict__ bias,
                                                 float* __restrict__ Y, int N) {
    int wid = threadIdx.x >> 6, lane = threadIdx.x & 63;
    int v = blockIdx.x * 4 + wid;
    if (v >= N) return;

    float2 acc = bfpair(Gq[v * 64 + lane]);
    int e = rp[v], end = rp[v + 1];
    for (; e + 8 <= end; e += 8) {
        int u[8];
#pragma unroll
        for (int j = 0; j < 8; ++j) u[j] = col[e + j];
        u32 q[8];
#pragma unroll
        for (int j = 0; j < 8; ++j) q[j] = Gq[u[j] * 64 + lane];
#pragma unroll
        for (int j = 0; j < 8; ++j) {
            float2 a = bfpair(q[j]);
            acc.x += a.x; acc.y += a.y;
        }
    }
    for (; e < end; ++e) {
        float2 a = bfpair(Gq[col[e] * 64 + lane]);
        acc.x += a.x; acc.y += a.y;
    }
    float s = dinv[v];
    float rx = acc.x * s;
    float ry = acc.y * s;
    if (HAS_BIAS) { rx += bias[2 * lane]; ry += bias[2 * lane + 1]; }
    if (RELU) { rx = fmaxf(rx, 0.f); ry = fmaxf(ry, 0.f); }
    float2 o2; o2.x = rx; o2.y = ry;
    *(float2*)(Y + (size_t)v * 128 + 2 * lane) = o2;
}

// ---------------------------------------------------------------------------
// SpMM-64 (bf16 in): lane <-> channel. Optional bf16 out.
// ---------------------------------------------------------------------------
template <bool OUT_BF16, bool RELU, bool HAS_BIAS, bool PRESCALE>
__global__ __launch_bounds__(256) void k_spmm64(const u16* __restrict__ G16,
                                                const int* __restrict__ rp,
                                                const int* __restrict__ col,
                                                const float* __restrict__ dinv,
                                                const float* __restrict__ bias,
                                                void* __restrict__ Y, int N) {
    int wid = threadIdx.x >> 6, lane = threadIdx.x & 63;
    int v = blockIdx.x * 4 + wid;
    if (v >= N) return;

    float acc = bf2f(G16[v * 64 + lane]);
    int e = rp[v], end = rp[v + 1];
    for (; e + 8 <= end; e += 8) {
        int u[8];
#pragma unroll
        for (int j = 0; j < 8; ++j) u[j] = col[e + j];
        u16 g[8];
#pragma unroll
        for (int j = 0; j < 8; ++j) g[j] = G16[u[j] * 64 + lane];
        acc += ((bf2f(g[0]) + bf2f(g[1])) + (bf2f(g[2]) + bf2f(g[3]))) +
               ((bf2f(g[4]) + bf2f(g[5])) + (bf2f(g[6]) + bf2f(g[7])));
    }
    for (; e < end; ++e) acc += bf2f(G16[col[e] * 64 + lane]);

    float s = dinv[v];
    float r = acc * s;
    if (HAS_BIAS) r += bias[lane];
    if (RELU) r = fmaxf(r, 0.f);
    if (PRESCALE) r *= s;
    if (OUT_BF16) ((u16*)Y)[v * 64 + lane] = f2bf_rne(r);
    else          ((float*)Y)[v * 64 + lane] = r;
}

// ---------------------------------------------------------------------------
extern "C" void kernel_launch(void* const* d_in, const int* in_sizes, int n_in,
                              void* d_out, int out_size, void* d_ws, size_t ws_size,
                              hipStream_t stream) {
    const float* x  = (const float*)d_in[0];
    const void*  ei = d_in[1];
    const float* W1 = (const float*)d_in[2];
    const float* b1 = (const float*)d_in[3];
    const float* W2 = (const float*)d_in[4];
    const float* b2 = (const float*)d_in[5];
    const float* W3 = (const float*)d_in[6];
    const float* b3 = (const float*)d_in[7];
    const float* W4 = (const float*)d_in[8];
    const float* b4 = (const float*)d_in[9];

    const int N = in_sizes[0] / 128;   // 100000
    const int E = in_sizes[1] / 2;     // 1600000

    // workspace carve-up (256B aligned)
    size_t off = 0;
    auto alloc = [&](size_t bytes) -> void* {
        void* p = (char*)d_ws + off;
        off += (bytes + 255) & ~(size_t)255;
        return p;
    };
    u32*   flag    = (u32*)  alloc(4);
    int*   src32   = (int*)  alloc((size_t)E * 4);
    int*   dst32   = (int*)  alloc((size_t)E * 4);   // contiguous with src32
    u32*   deg     = (u32*)  alloc((size_t)N * 4);
    float* dinv    = (float*)alloc((size_t)N * 4);
    int*   row_ptr = (int*)  alloc((size_t)(N + 1) * 4);
    u32*   cnt     = (u32*)  alloc((size_t)N * 4);
    u32*   partial = (u32*)  alloc(256 * 4);
    int*   col     = (int*)  alloc((size_t)E * 4);
    float* A       = (float*)alloc((size_t)N * 128 * 4);   // f32 view / bf16 view
    float* B       = (float*)alloc((size_t)N * 128 * 4);   // f32 view / bf16 view
    u16*   Zbf     = (u16*)d_out;    // zh (N x 64 bf16) borrows d_out; overwritten at the end

    const int n2 = 2 * E;
    const int NB = (N + 1023) / 1024;

    // graph preprocessing
    k_detect<<<1, 256, 0, stream>>>((const int*)ei, n2, flag);
    k_convert<<<(n2 + 255) / 256, 256, 0, stream>>>(ei, n2, flag, src32);  // [0..E)=src, [E..2E)=dst
    int* dstp = src32 + E;
    k_init<<<(N + 255) / 256, 256, 0, stream>>>(deg, cnt, N);
    k_count<<<1024, 256, 0, stream>>>(dstp, deg, E, N);
    k_dinv<<<(N + 255) / 256, 256, 0, stream>>>(deg, dinv, N);
    k_scan_a<<<NB, 256, 0, stream>>>(deg, partial, N);
    k_scan_b<<<1, 128, 0, stream>>>(partial, NB, row_ptr, N);
    k_scan_c<<<NB, 256, 0, stream>>>(deg, partial, row_ptr, N);
    k_fill<<<1024, 256, 0, stream>>>(src32, dstp, row_ptr, cnt, col, E, N);
    (void)dst32;

    const int gG = (N + 63) / 64;    // gemm grid
    const int gS = (N + 3) / 4;      // spmm grid

    // Layer 1: G1 = (x@W1ᵀ)·dinv -> bf16 ; h1 = relu(agg + b1) f32
    k_gemm<128, 128, 0, true><<<gG, 256, 0, stream>>>(x, W1, dinv, A, N);
    k_spmm128<true, true><<<gS, 256, 0, stream>>>((const u32*)A, row_ptr, col, dinv, b1, B, N);

    // Layer 2: G2 = (h1@W2ᵀ)·dinv -> bf16 ; zh = dinv·(agg + b2) -> bf16
    k_gemm<128, 64, 0, true><<<gG, 256, 0, stream>>>(B, W2, dinv, A, N);
    k_spmm64<true, false, true, true><<<gS, 256, 0, stream>>>((const u16*)A, row_ptr, col, dinv, b2, Zbf, N);

    // Layer 3 (reordered): aggz = dinv·(zh + sum zh) f32 ; h3 = relu(aggz@W3ᵀ + b3) f32
    k_spmm64<false, false, false, false><<<gS, 256, 0, stream>>>(Zbf, row_ptr, col, dinv, b2, B, N);
    k_gemm<64, 128, 1, false><<<gG, 256, 0, stream>>>(B, W3, b3, A, N);   // A = h3 f32

    // Layer 4: G4 = (h3@W4ᵀ)·dinv -> bf16 (B region) ; out = agg·dinv + b4
    k_gemm<128, 128, 0, true><<<gG, 256, 0, stream>>>(A, W4, dinv, B, N);
    k_spmm128<false, true><<<gS, 256, 0, stream>>>((const u32*)B, row_ptr, col, dinv, b4, (float*)d_out, N);
}

// Round 6
// 527.072 us; speedup vs baseline: 2.3456x; 1.2765x over previous
//
#include <hip/hip_runtime.h>

typedef unsigned int u32;
typedef unsigned short u16;
typedef short bf16x4 __attribute__((ext_vector_type(4)));
typedef short bf16x8 __attribute__((ext_vector_type(8)));
typedef float f32x4 __attribute__((ext_vector_type(4)));

// bf16 helpers: round-to-nearest-even pack, cheap unpack
__device__ inline u16 f2bf_rne(float f) {
    u32 b = __float_as_uint(f);
    return (u16)((b + 0x7FFFu + ((b >> 16) & 1u)) >> 16);
}
__device__ inline u32 packbf2(float lo, float hi) {
    return (u32)f2bf_rne(lo) | ((u32)f2bf_rne(hi) << 16);
}
__device__ inline float bf2f(u16 h) { return __uint_as_float((u32)h << 16); }
__device__ inline float2 bfpair(u32 q) {
    float2 f;
    f.x = __uint_as_float(q << 16);
    f.y = __uint_as_float(q & 0xFFFF0000u);
    return f;
}

// ---------------------------------------------------------------------------
// Edge-index dtype detection (int64 vs int32 buffer)
// ---------------------------------------------------------------------------
__global__ void k_detect(const int* __restrict__ p, int n_int32, u32* __restrict__ flag) {
    __shared__ int s[256];
    int tid = threadIdx.x;
    int acc = 0;
    int limit = n_int32 < 2048 ? n_int32 : 2048;
    for (int i = 1 + 2 * tid; i < limit; i += 512) acc |= p[i];
    s[tid] = acc;
    __syncthreads();
    for (int o = 128; o > 0; o >>= 1) {
        if (tid < o) s[tid] |= s[tid + o];
        __syncthreads();
    }
    if (tid == 0) *flag = (s[0] == 0) ? 1u : 0u;
}

__global__ void k_convert(const void* __restrict__ p, int n, const u32* __restrict__ flag,
                          int* __restrict__ out) {
    int i = blockIdx.x * blockDim.x + threadIdx.x;
    if (i >= n) return;
    if (*flag) out[i] = (int)((const long long*)p)[i];
    else       out[i] = ((const int*)p)[i];
}

// f32 -> bf16 conversion (n must be a multiple of 8)
__global__ void k_cvt(const float* __restrict__ in, u16* __restrict__ out, int n) {
    int i = (blockIdx.x * 256 + threadIdx.x) * 8;
    int stride = gridDim.x * 256 * 8;
    for (; i + 8 <= n; i += stride) {
        float4 a = *(const float4*)(in + i);
        float4 b = *(const float4*)(in + i + 4);
        uint4 o;
        o.x = packbf2(a.x, a.y);
        o.y = packbf2(a.z, a.w);
        o.z = packbf2(b.x, b.y);
        o.w = packbf2(b.z, b.w);
        *(uint4*)(out + i) = o;
    }
}

// ---------------------------------------------------------------------------
// Degree / dinv / CSR build
// ---------------------------------------------------------------------------
__global__ void k_init(u32* __restrict__ deg, u32* __restrict__ cnt, int N) {
    int i = blockIdx.x * blockDim.x + threadIdx.x;
    if (i < N) { deg[i] = 1u; cnt[i] = 0u; }  // deg starts at 1 (self-loop)
}

// XCD-range-partitioned degree count (keeps atomic lines in one XCD's L2)
__global__ __launch_bounds__(256) void k_count(const int* __restrict__ dst,
                                               u32* __restrict__ deg, int E, int N) {
    int xcd = blockIdx.x & 7;
    int sub = blockIdx.x >> 3;
    int nsub = gridDim.x >> 3;
    int lo = (int)((long long)N * xcd >> 3);
    int hi = (int)((long long)N * (xcd + 1) >> 3);
    for (int e = sub * 256 + threadIdx.x; e < E; e += nsub * 256) {
        int d = dst[e];
        if (d >= lo && d < hi) atomicAdd(&deg[d], 1u);
    }
}

__global__ void k_dinv(const u32* __restrict__ deg, float* __restrict__ dinv, int N) {
    int i = blockIdx.x * blockDim.x + threadIdx.x;
    if (i < N) dinv[i] = rsqrtf((float)deg[i]);
}

// 3-phase exclusive scan of (deg[v]-1) -> row_ptr
__global__ void k_scan_a(const u32* __restrict__ deg, u32* __restrict__ partial, int N) {
    __shared__ u32 s[256];
    int tid = threadIdx.x;
    int base = blockIdx.x * 1024 + tid * 4;
    u32 sum = 0;
#pragma unroll
    for (int j = 0; j < 4; ++j) {
        int v = base + j;
        sum += (v < N) ? (deg[v] - 1u) : 0u;
    }
    s[tid] = sum;
    __syncthreads();
    for (int o = 128; o > 0; o >>= 1) {
        if (tid < o) s[tid] += s[tid + o];
        __syncthreads();
    }
    if (tid == 0) partial[blockIdx.x] = s[0];
}

__global__ void k_scan_b(u32* __restrict__ partial, int NB, int* __restrict__ row_ptr, int N) {
    __shared__ u32 s[128];
    int tid = threadIdx.x;
    u32 v = (tid < NB) ? partial[tid] : 0u;
    s[tid] = v;
    __syncthreads();
    for (int off = 1; off < 128; off <<= 1) {
        u32 t = (tid >= off) ? s[tid - off] : 0u;
        __syncthreads();
        s[tid] += t;
        __syncthreads();
    }
    if (tid < NB) partial[tid] = s[tid] - v;
    if (tid == 127) row_ptr[N] = (int)s[127];
}

__global__ void k_scan_c(const u32* __restrict__ deg, const u32* __restrict__ partial,
                         int* __restrict__ row_ptr, int N) {
    __shared__ u32 s[256];
    int tid = threadIdx.x;
    int base = blockIdx.x * 1024 + tid * 4;
    u32 vals[4];
    u32 sum = 0;
#pragma unroll
    for (int j = 0; j < 4; ++j) {
        int v = base + j;
        vals[j] = (v < N) ? (deg[v] - 1u) : 0u;
        sum += vals[j];
    }
    s[tid] = sum;
    __syncthreads();
    for (int off = 1; off < 256; off <<= 1) {
        u32 t = (tid >= off) ? s[tid - off] : 0u;
        __syncthreads();
        s[tid] += t;
        __syncthreads();
    }
    u32 run = s[tid] - sum + partial[blockIdx.x];
#pragma unroll
    for (int j = 0; j < 4; ++j) {
        int v = base + j;
        if (v < N) row_ptr[v] = (int)run;
        run += vals[j];
    }
}

// XCD-range-partitioned CSR fill
__global__ __launch_bounds__(256) void k_fill(const int* __restrict__ src,
                                              const int* __restrict__ dst,
                                              const int* __restrict__ row_ptr,
                                              u32* __restrict__ cnt,
                                              int* __restrict__ col, int E, int N) {
    int xcd = blockIdx.x & 7;
    int sub = blockIdx.x >> 3;
    int nsub = gridDim.x >> 3;
    int lo = (int)((long long)N * xcd >> 3);
    int hi = (int)((long long)N * (xcd + 1) >> 3);
    for (int e = sub * 256 + threadIdx.x; e < E; e += nsub * 256) {
        int d = dst[e];
        if (d >= lo && d < hi) {
            int pos = row_ptr[d] + (int)atomicAdd(&cnt[d], 1u);
            col[pos] = src[e];
        }
    }
}

// ---------------------------------------------------------------------------
// MFMA GEMM (bf16 in, bf16 out): Gout[row][o] = epi( sum_k Xb[row][k]*Wb[o][k] )
//   MODE 0: epi = acc * dinv[row]   (aux = dinv)
//   MODE 1: epi = relu(acc + bias)  (aux = bias)
// Block 256 thr = 4 waves, 64 rows/block (16 rows/wave), full K staged in LDS.
// v_mfma_f32_16x16x32_bf16 fragment layout:
//   A: lane holds A[lane&15][k=4*(lane>>4)+(e&3)+16*(e>>2)]  (two b64 at k, k+16)
//   B: lane holds B[k same][lane&15]  = W[lane&15-col][k]
//   D: lane reg i holds D[4*(lane>>4)+i][lane&15]            (m89-verified)
// ---------------------------------------------------------------------------
template <int CIN, int COUT, int MODE>
__global__ __launch_bounds__(256) void k_mgemm(const u16* __restrict__ Xb,
                                               const u16* __restrict__ Wb,
                                               const float* __restrict__ aux,
                                               u16* __restrict__ Gout, int N) {
    constexpr int PITCH = CIN + 8;        // bf16 units; row stride 16B-aligned
    constexpr int NT = COUT / 16;         // output col-tiles
    constexpr int KS = CIN / 32;          // mfma k-steps
    __shared__ __align__(16) u16 sX[64 * PITCH];
    __shared__ __align__(16) u16 sW[COUT * PITCH];

    int tid = threadIdx.x, wid = tid >> 6, lane = tid & 63;
    int l15 = lane & 15, l4 = lane >> 4;
    int rowbase = blockIdx.x * 64;

    // stage W tile (bf16x8 per thread per iter, coalesced)
    for (int i = tid * 8; i < COUT * CIN; i += 256 * 8) {
        int o = i / CIN, k = i % CIN;
        *(bf16x8*)&sW[o * PITCH + k] = *(const bf16x8*)&Wb[i];
    }
    // stage X tile
    for (int i = tid * 8; i < 64 * CIN; i += 256 * 8) {
        int r = i / CIN, k = i % CIN;
        int row = rowbase + r;
        if (row >= N) row = N - 1;        // clamp; stores guarded below
        *(bf16x8*)&sX[r * PITCH + k] = *(const bf16x8*)&Xb[(size_t)row * CIN + k];
    }
    __syncthreads();

    f32x4 acc[NT];
#pragma unroll
    for (int nt = 0; nt < NT; ++nt) acc[nt] = (f32x4){0.f, 0.f, 0.f, 0.f};

    const u16* xrow = &sX[(wid * 16 + l15) * PITCH + 4 * l4];
    const u16* wrow = &sW[l15 * PITCH + 4 * l4];

#pragma unroll
    for (int ks = 0; ks < KS; ++ks) {
        bf16x4 a0 = *(const bf16x4*)(xrow + ks * 32);
        bf16x4 a1 = *(const bf16x4*)(xrow + ks * 32 + 16);
        bf16x8 av = __builtin_shufflevector(a0, a1, 0, 1, 2, 3, 4, 5, 6, 7);
#pragma unroll
        for (int nt = 0; nt < NT; ++nt) {
            const u16* bp = wrow + nt * 16 * PITCH + ks * 32;
            bf16x4 b0 = *(const bf16x4*)bp;
            bf16x4 b1 = *(const bf16x4*)(bp + 16);
            bf16x8 bv = __builtin_shufflevector(b0, b1, 0, 1, 2, 3, 4, 5, 6, 7);
            acc[nt] = __builtin_amdgcn_mfma_f32_16x16x32_bf16(av, bv, acc[nt], 0, 0, 0);
        }
    }

    // epilogue: lane reg i -> row rowbase + wid*16 + 4*l4 + i, col nt*16 + l15
    float bv[NT];
    if (MODE == 1) {
#pragma unroll
        for (int nt = 0; nt < NT; ++nt) bv[nt] = aux[nt * 16 + l15];
    }
#pragma unroll
    for (int i = 0; i < 4; ++i) {
        int row = rowbase + wid * 16 + 4 * l4 + i;
        if (row < N) {
            float s = (MODE == 0) ? aux[row] : 0.f;
#pragma unroll
            for (int nt = 0; nt < NT; ++nt) {
                float a = acc[nt][i];
                float o = (MODE == 0) ? a * s : fmaxf(a + bv[nt], 0.f);
                Gout[(size_t)row * COUT + nt * 16 + l15] = f2bf_rne(o);
            }
        }
    }
}

// ---------------------------------------------------------------------------
// SpMM-128 (bf16 in): acc = G[v] + sum G[col[e]]; r = acc*dinv[v] (+bias, relu)
// Lane holds channel pair (2*lane, 2*lane+1) packed in one u32.
// ---------------------------------------------------------------------------
template <bool OUT_BF16, bool RELU, bool HAS_BIAS>
__global__ __launch_bounds__(256) void k_spmm128(const u32* __restrict__ Gq,
                                                 const int* __restrict__ rp,
                                                 const int* __restrict__ col,
                                                 const float* __restrict__ dinv,
                                                 const float* __restrict__ bias,
                                                 void* __restrict__ Y, int N) {
    int wid = threadIdx.x >> 6, lane = threadIdx.x & 63;
    int v = blockIdx.x * 4 + wid;
    if (v >= N) return;

    float2 acc = bfpair(Gq[v * 64 + lane]);
    int e = rp[v], end = rp[v + 1];
    for (; e + 8 <= end; e += 8) {
        int u[8];
#pragma unroll
        for (int j = 0; j < 8; ++j) u[j] = col[e + j];
        u32 q[8];
#pragma unroll
        for (int j = 0; j < 8; ++j) q[j] = Gq[u[j] * 64 + lane];
#pragma unroll
        for (int j = 0; j < 8; ++j) {
            float2 a = bfpair(q[j]);
            acc.x += a.x; acc.y += a.y;
        }
    }
    for (; e < end; ++e) {
        float2 a = bfpair(Gq[col[e] * 64 + lane]);
        acc.x += a.x; acc.y += a.y;
    }
    float s = dinv[v];
    float rx = acc.x * s;
    float ry = acc.y * s;
    if (HAS_BIAS) { rx += bias[2 * lane]; ry += bias[2 * lane + 1]; }
    if (RELU) { rx = fmaxf(rx, 0.f); ry = fmaxf(ry, 0.f); }
    if (OUT_BF16) {
        ((u32*)Y)[v * 64 + lane] = packbf2(rx, ry);
    } else {
        float2 o2; o2.x = rx; o2.y = ry;
        *(float2*)((float*)Y + (size_t)v * 128 + 2 * lane) = o2;
    }
}

// ---------------------------------------------------------------------------
// SpMM-64 (bf16 in): lane <-> channel. Optional bf16 out.
// ---------------------------------------------------------------------------
template <bool OUT_BF16, bool RELU, bool HAS_BIAS, bool PRESCALE>
__global__ __launch_bounds__(256) void k_spmm64(const u16* __restrict__ G16,
                                                const int* __restrict__ rp,
                                                const int* __restrict__ col,
                                                const float* __restrict__ dinv,
                                                const float* __restrict__ bias,
                                                void* __restrict__ Y, int N) {
    int wid = threadIdx.x >> 6, lane = threadIdx.x & 63;
    int v = blockIdx.x * 4 + wid;
    if (v >= N) return;

    float acc = bf2f(G16[v * 64 + lane]);
    int e = rp[v], end = rp[v + 1];
    for (; e + 8 <= end; e += 8) {
        int u[8];
#pragma unroll
        for (int j = 0; j < 8; ++j) u[j] = col[e + j];
        u16 g[8];
#pragma unroll
        for (int j = 0; j < 8; ++j) g[j] = G16[u[j] * 64 + lane];
        acc += ((bf2f(g[0]) + bf2f(g[1])) + (bf2f(g[2]) + bf2f(g[3]))) +
               ((bf2f(g[4]) + bf2f(g[5])) + (bf2f(g[6]) + bf2f(g[7])));
    }
    for (; e < end; ++e) acc += bf2f(G16[col[e] * 64 + lane]);

    float s = dinv[v];
    float r = acc * s;
    if (HAS_BIAS) r += bias[lane];
    if (RELU) r = fmaxf(r, 0.f);
    if (PRESCALE) r *= s;
    if (OUT_BF16) ((u16*)Y)[v * 64 + lane] = f2bf_rne(r);
    else          ((float*)Y)[v * 64 + lane] = r;
}

// ---------------------------------------------------------------------------
extern "C" void kernel_launch(void* const* d_in, const int* in_sizes, int n_in,
                              void* d_out, int out_size, void* d_ws, size_t ws_size,
                              hipStream_t stream) {
    const float* x  = (const float*)d_in[0];
    const void*  ei = d_in[1];
    const float* W1 = (const float*)d_in[2];
    const float* b1 = (const float*)d_in[3];
    const float* W2 = (const float*)d_in[4];
    const float* b2 = (const float*)d_in[5];
    const float* W3 = (const float*)d_in[6];
    const float* b3 = (const float*)d_in[7];
    const float* W4 = (const float*)d_in[8];
    const float* b4 = (const float*)d_in[9];

    const int N = in_sizes[0] / 128;   // 100000
    const int E = in_sizes[1] / 2;     // 1600000

    // workspace carve-up (256B aligned)
    size_t off = 0;
    auto alloc = [&](size_t bytes) -> void* {
        void* p = (char*)d_ws + off;
        off += (bytes + 255) & ~(size_t)255;
        return p;
    };
    u32*   flag    = (u32*)  alloc(4);
    int*   src32   = (int*)  alloc((size_t)E * 4);
    int*   dst32   = (int*)  alloc((size_t)E * 4);   // contiguous with src32
    u32*   deg     = (u32*)  alloc((size_t)N * 4);
    float* dinv    = (float*)alloc((size_t)N * 4);
    int*   row_ptr = (int*)  alloc((size_t)(N + 1) * 4);
    u32*   cnt     = (u32*)  alloc((size_t)N * 4);
    u32*   partial = (u32*)  alloc(256 * 4);
    int*   col     = (int*)  alloc((size_t)E * 4);
    u16*   xb      = (u16*)  alloc((size_t)N * 128 * 2);   // x as bf16
    u16*   Wb1     = (u16*)  alloc(128 * 128 * 2);
    u16*   Wb2     = (u16*)  alloc(64 * 128 * 2);
    u16*   Wb3     = (u16*)  alloc(128 * 64 * 2);
    u16*   Wb4     = (u16*)  alloc(128 * 128 * 2);
    u16*   BUF1    = (u16*)  alloc((size_t)N * 128 * 2);   // Ga / aggz / G4
    u16*   BUF2    = (u16*)  alloc((size_t)N * 128 * 2);   // h1 / h3
    u16*   BUF3    = (u16*)  alloc((size_t)N * 64 * 2);    // G2
    u16*   Zbf     = (u16*)d_out;   // zh (N x 64 bf16) borrows d_out; dead before final write

    const int n2 = 2 * E;
    const int NB = (N + 1023) / 1024;

    // graph preprocessing
    k_detect<<<1, 256, 0, stream>>>((const int*)ei, n2, flag);
    k_convert<<<(n2 + 255) / 256, 256, 0, stream>>>(ei, n2, flag, src32);  // [0..E)=src, [E..2E)=dst
    int* dstp = src32 + E;
    k_init<<<(N + 255) / 256, 256, 0, stream>>>(deg, cnt, N);
    k_count<<<1024, 256, 0, stream>>>(dstp, deg, E, N);
    k_dinv<<<(N + 255) / 256, 256, 0, stream>>>(deg, dinv, N);
    k_scan_a<<<NB, 256, 0, stream>>>(deg, partial, N);
    k_scan_b<<<1, 128, 0, stream>>>(partial, NB, row_ptr, N);
    k_scan_c<<<NB, 256, 0, stream>>>(deg, partial, row_ptr, N);
    k_fill<<<1024, 256, 0, stream>>>(src32, dstp, row_ptr, cnt, col, E, N);
    (void)dst32;

    // bf16 conversions
    k_cvt<<<1024, 256, 0, stream>>>(x, xb, N * 128);
    k_cvt<<<8, 256, 0, stream>>>(W1, Wb1, 128 * 128);
    k_cvt<<<8, 256, 0, stream>>>(W2, Wb2, 64 * 128);
    k_cvt<<<8, 256, 0, stream>>>(W3, Wb3, 128 * 64);
    k_cvt<<<8, 256, 0, stream>>>(W4, Wb4, 128 * 128);

    const int gM = (N + 63) / 64;    // mgemm grid
    const int gS = (N + 3) / 4;      // spmm grid

    // Layer 1: G1 = (x@W1ᵀ)·dinv ; h1 = relu(agg + b1) -> bf16
    k_mgemm<128, 128, 0><<<gM, 256, 0, stream>>>(xb, Wb1, dinv, BUF1, N);
    k_spmm128<true, true, true><<<gS, 256, 0, stream>>>((const u32*)BUF1, row_ptr, col, dinv, b1, BUF2, N);

    // Layer 2: G2 = (h1@W2ᵀ)·dinv ; zh = dinv·(agg + b2) -> bf16 (in d_out)
    k_mgemm<128, 64, 0><<<gM, 256, 0, stream>>>(BUF2, Wb2, dinv, BUF3, N);
    k_spmm64<true, false, true, true><<<gS, 256, 0, stream>>>(BUF3, row_ptr, col, dinv, b2, Zbf, N);

    // Layer 3 (reordered): aggz = dinv·(zh + sum zh) -> bf16 ; h3 = relu(aggz@W3ᵀ + b3) -> bf16
    k_spmm64<true, false, false, false><<<gS, 256, 0, stream>>>(Zbf, row_ptr, col, dinv, b2, BUF1, N);
    k_mgemm<64, 128, 1><<<gM, 256, 0, stream>>>(BUF1, Wb3, b3, BUF2, N);

    // Layer 4: G4 = (h3@W4ᵀ)·dinv ; out = agg·dinv + b4 -> f32 d_out
    k_mgemm<128, 128, 0><<<gM, 256, 0, stream>>>(BUF2, Wb4, dinv, BUF1, N);
    k_spmm128<false, false, true><<<gS, 256, 0, stream>>>((const u32*)BUF1, row_ptr, col, dinv, b4, d_out, N);
}

// Round 7
// 510.206 us; speedup vs baseline: 2.4231x; 1.0331x over previous
//
#include <hip/hip_runtime.h>

typedef unsigned int u32;
typedef unsigned short u16;
typedef short bf16x4 __attribute__((ext_vector_type(4)));
typedef short bf16x8 __attribute__((ext_vector_type(8)));
typedef float f32x4 __attribute__((ext_vector_type(4)));

// bf16 helpers: round-to-nearest-even pack, cheap unpack
__device__ inline u16 f2bf_rne(float f) {
    u32 b = __float_as_uint(f);
    return (u16)((b + 0x7FFFu + ((b >> 16) & 1u)) >> 16);
}
__device__ inline u32 packbf2(float lo, float hi) {
    return (u32)f2bf_rne(lo) | ((u32)f2bf_rne(hi) << 16);
}
__device__ inline float bf2f(u16 h) { return __uint_as_float((u32)h << 16); }
__device__ inline float2 bfpair(u32 q) {
    float2 f;
    f.x = __uint_as_float(q << 16);
    f.y = __uint_as_float(q & 0xFFFF0000u);
    return f;
}

// ---------------------------------------------------------------------------
// Edge-index dtype detection (int64 vs int32 buffer)
// ---------------------------------------------------------------------------
__global__ void k_detect(const int* __restrict__ p, int n_int32, u32* __restrict__ flag) {
    __shared__ int s[256];
    int tid = threadIdx.x;
    int acc = 0;
    int limit = n_int32 < 2048 ? n_int32 : 2048;
    for (int i = 1 + 2 * tid; i < limit; i += 512) acc |= p[i];
    s[tid] = acc;
    __syncthreads();
    for (int o = 128; o > 0; o >>= 1) {
        if (tid < o) s[tid] |= s[tid + o];
        __syncthreads();
    }
    if (tid == 0) *flag = (s[0] == 0) ? 1u : 0u;
}

__global__ void k_convert(const void* __restrict__ p, int n, const u32* __restrict__ flag,
                          int* __restrict__ out) {
    int i = blockIdx.x * blockDim.x + threadIdx.x;
    if (i >= n) return;
    if (*flag) out[i] = (int)((const long long*)p)[i];
    else       out[i] = ((const int*)p)[i];
}

// f32 -> bf16 conversion (n must be a multiple of 8)
__global__ void k_cvt(const float* __restrict__ in, u16* __restrict__ out, int n) {
    int i = (blockIdx.x * 256 + threadIdx.x) * 8;
    int stride = gridDim.x * 256 * 8;
    for (; i + 8 <= n; i += stride) {
        float4 a = *(const float4*)(in + i);
        float4 b = *(const float4*)(in + i + 4);
        uint4 o;
        o.x = packbf2(a.x, a.y);
        o.y = packbf2(a.z, a.w);
        o.z = packbf2(b.x, b.y);
        o.w = packbf2(b.z, b.w);
        *(uint4*)(out + i) = o;
    }
}

// Pack W (f32 [COUT][CIN]) into mfma B-fragment register order (bf16):
// Wpk[((nt*KS + ks)*64 + lane)*8 + e] = bf16(W[nt*16+l15][ks*32 + 4*l4 + (e&3) + 16*(e>>2)])
// where lane = l4*16 + l15. A wave then loads fragment (nt,ks) as one
// coalesced 16B/lane (1KB/wave) global read.
template <int CIN, int COUT>
__global__ void k_wpack(const float* __restrict__ W, u16* __restrict__ Wpk) {
    int i = blockIdx.x * 256 + threadIdx.x;
    if (i >= CIN * COUT) return;
    int o = i / CIN, k = i % CIN;
    int nt = o >> 4, l15 = o & 15;
    int ks = k >> 5, w = k & 31;
    int h = w >> 4, l4 = (w & 15) >> 2, off = w & 3;
    int lane = l4 * 16 + l15;
    int e = h * 4 + off;
    constexpr int KS = CIN / 32;
    Wpk[(size_t)(((nt * KS + ks) * 64 + lane) * 8 + e)] = f2bf_rne(W[i]);
}

// ---------------------------------------------------------------------------
// Degree / dinv / CSR build
// ---------------------------------------------------------------------------
__global__ void k_init(u32* __restrict__ deg, u32* __restrict__ cnt, int N) {
    int i = blockIdx.x * blockDim.x + threadIdx.x;
    if (i < N) { deg[i] = 1u; cnt[i] = 0u; }  // deg starts at 1 (self-loop)
}

// XCD-range-partitioned degree count (keeps atomic lines in one XCD's L2)
__global__ __launch_bounds__(256) void k_count(const int* __restrict__ dst,
                                               u32* __restrict__ deg, int E, int N) {
    int xcd = blockIdx.x & 7;
    int sub = blockIdx.x >> 3;
    int nsub = gridDim.x >> 3;
    int lo = (int)((long long)N * xcd >> 3);
    int hi = (int)((long long)N * (xcd + 1) >> 3);
    for (int e = sub * 256 + threadIdx.x; e < E; e += nsub * 256) {
        int d = dst[e];
        if (d >= lo && d < hi) atomicAdd(&deg[d], 1u);
    }
}

__global__ void k_dinv(const u32* __restrict__ deg, float* __restrict__ dinv, int N) {
    int i = blockIdx.x * blockDim.x + threadIdx.x;
    if (i < N) dinv[i] = rsqrtf((float)deg[i]);
}

// 3-phase exclusive scan of (deg[v]-1) -> row_ptr
__global__ void k_scan_a(const u32* __restrict__ deg, u32* __restrict__ partial, int N) {
    __shared__ u32 s[256];
    int tid = threadIdx.x;
    int base = blockIdx.x * 1024 + tid * 4;
    u32 sum = 0;
#pragma unroll
    for (int j = 0; j < 4; ++j) {
        int v = base + j;
        sum += (v < N) ? (deg[v] - 1u) : 0u;
    }
    s[tid] = sum;
    __syncthreads();
    for (int o = 128; o > 0; o >>= 1) {
        if (tid < o) s[tid] += s[tid + o];
        __syncthreads();
    }
    if (tid == 0) partial[blockIdx.x] = s[0];
}

__global__ void k_scan_b(u32* __restrict__ partial, int NB, int* __restrict__ row_ptr, int N) {
    __shared__ u32 s[128];
    int tid = threadIdx.x;
    u32 v = (tid < NB) ? partial[tid] : 0u;
    s[tid] = v;
    __syncthreads();
    for (int off = 1; off < 128; off <<= 1) {
        u32 t = (tid >= off) ? s[tid - off] : 0u;
        __syncthreads();
        s[tid] += t;
        __syncthreads();
    }
    if (tid < NB) partial[tid] = s[tid] - v;
    if (tid == 127) row_ptr[N] = (int)s[127];
}

__global__ void k_scan_c(const u32* __restrict__ deg, const u32* __restrict__ partial,
                         int* __restrict__ row_ptr, int N) {
    __shared__ u32 s[256];
    int tid = threadIdx.x;
    int base = blockIdx.x * 1024 + tid * 4;
    u32 vals[4];
    u32 sum = 0;
#pragma unroll
    for (int j = 0; j < 4; ++j) {
        int v = base + j;
        vals[j] = (v < N) ? (deg[v] - 1u) : 0u;
        sum += vals[j];
    }
    s[tid] = sum;
    __syncthreads();
    for (int off = 1; off < 256; off <<= 1) {
        u32 t = (tid >= off) ? s[tid - off] : 0u;
        __syncthreads();
        s[tid] += t;
        __syncthreads();
    }
    u32 run = s[tid] - sum + partial[blockIdx.x];
#pragma unroll
    for (int j = 0; j < 4; ++j) {
        int v = base + j;
        if (v < N) row_ptr[v] = (int)run;
        run += vals[j];
    }
}

// XCD-range-partitioned CSR fill
__global__ __launch_bounds__(256) void k_fill(const int* __restrict__ src,
                                              const int* __restrict__ dst,
                                              const int* __restrict__ row_ptr,
                                              u32* __restrict__ cnt,
                                              int* __restrict__ col, int E, int N) {
    int xcd = blockIdx.x & 7;
    int sub = blockIdx.x >> 3;
    int nsub = gridDim.x >> 3;
    int lo = (int)((long long)N * xcd >> 3);
    int hi = (int)((long long)N * (xcd + 1) >> 3);
    for (int e = sub * 256 + threadIdx.x; e < E; e += nsub * 256) {
        int d = dst[e];
        if (d >= lo && d < hi) {
            int pos = row_ptr[d] + (int)atomicAdd(&cnt[d], 1u);
            col[pos] = src[e];
        }
    }
}

// ---------------------------------------------------------------------------
// MFMA GEMM v2 (bf16 in, bf16 out): Gout[row][o] = epi( sum_k X[row][k]*W[o][k] )
//   MODE 0: epi = acc * dinv[row]   (aux = dinv)
//   MODE 1: epi = relu(acc + bias)  (aux = bias)
// W held ENTIRELY in VGPRs (fragment order from k_wpack, coalesced global
// loads). LDS holds only the X tile. Inner loop: 2 ds_read_b64 + NT mfma
// per k-step. Block 256 thr = 4 waves, 64 rows/block (16 rows/wave).
// ---------------------------------------------------------------------------
template <int CIN, int COUT, int MODE>
__global__ __launch_bounds__(256, 2) void k_mgemm(const u16* __restrict__ Xb,
                                                  const u16* __restrict__ Wpk,
                                                  const float* __restrict__ aux,
                                                  u16* __restrict__ Gout, int N) {
    constexpr int PITCH = CIN + 8;        // u16 units; keeps b64 reads ~2-way
    constexpr int NT = COUT / 16;         // output col-tiles
    constexpr int KS = CIN / 32;          // mfma k-steps
    __shared__ __align__(16) u16 sX[64 * PITCH];

    int tid = threadIdx.x, wid = tid >> 6, lane = tid & 63;
    int l15 = lane & 15, l4 = lane >> 4;
    int rowbase = blockIdx.x * 64;

    // W fragments -> registers (L2-hot, 1KB/wave per fragment, coalesced)
    bf16x8 wfrag[NT][KS];
#pragma unroll
    for (int nt = 0; nt < NT; ++nt)
#pragma unroll
        for (int ks = 0; ks < KS; ++ks)
            wfrag[nt][ks] = *(const bf16x8*)&Wpk[(size_t)(((nt * KS + ks) * 64 + lane) * 8)];

    // stage X tile
    for (int i = tid * 8; i < 64 * CIN; i += 256 * 8) {
        int r = i / CIN, k = i % CIN;
        int row = rowbase + r;
        if (row >= N) row = N - 1;        // clamp; stores guarded below
        *(bf16x8*)&sX[r * PITCH + k] = *(const bf16x8*)&Xb[(size_t)row * CIN + k];
    }
    __syncthreads();

    f32x4 acc[NT];
#pragma unroll
    for (int nt = 0; nt < NT; ++nt) acc[nt] = (f32x4){0.f, 0.f, 0.f, 0.f};

    const u16* xrow = &sX[(wid * 16 + l15) * PITCH + 4 * l4];

#pragma unroll
    for (int ks = 0; ks < KS; ++ks) {
        bf16x4 a0 = *(const bf16x4*)(xrow + ks * 32);
        bf16x4 a1 = *(const bf16x4*)(xrow + ks * 32 + 16);
        bf16x8 av = __builtin_shufflevector(a0, a1, 0, 1, 2, 3, 4, 5, 6, 7);
#pragma unroll
        for (int nt = 0; nt < NT; ++nt)
            acc[nt] = __builtin_amdgcn_mfma_f32_16x16x32_bf16(av, wfrag[nt][ks], acc[nt], 0, 0, 0);
    }

    // epilogue: lane reg i -> row rowbase + wid*16 + 4*l4 + i, col nt*16 + l15
    float bv[NT];
    if (MODE == 1) {
#pragma unroll
        for (int nt = 0; nt < NT; ++nt) bv[nt] = aux[nt * 16 + l15];
    }
#pragma unroll
    for (int i = 0; i < 4; ++i) {
        int row = rowbase + wid * 16 + 4 * l4 + i;
        if (row < N) {
            float s = (MODE == 0) ? aux[row] : 0.f;
#pragma unroll
            for (int nt = 0; nt < NT; ++nt) {
                float a = acc[nt][i];
                float o = (MODE == 0) ? a * s : fmaxf(a + bv[nt], 0.f);
                Gout[(size_t)row * COUT + nt * 16 + l15] = f2bf_rne(o);
            }
        }
    }
}

// ---------------------------------------------------------------------------
// SpMM-128 (bf16 in): acc = G[v] + sum G[col[e]]; r = acc*dinv[v] (+bias, relu)
// Lane holds channel pair (2*lane, 2*lane+1) packed in one u32.
// TWO nodes per wave, dual 8-batches interleaved -> 16 gathers in flight.
// ---------------------------------------------------------------------------
template <bool OUT_BF16, bool RELU, bool HAS_BIAS>
__global__ __launch_bounds__(256) void k_spmm128(const u32* __restrict__ Gq,
                                                 const int* __restrict__ rp,
                                                 const int* __restrict__ col,
                                                 const float* __restrict__ dinv,
                                                 const float* __restrict__ bias,
                                                 void* __restrict__ Y, int N) {
    int wid = threadIdx.x >> 6, lane = threadIdx.x & 63;
    int v0 = blockIdx.x * 8 + wid * 2;
    if (v0 >= N) return;
    int v1 = v0 + 1;
    bool has1 = (v1 < N);

    float2 acc0 = bfpair(Gq[(size_t)v0 * 64 + lane]);
    int e0 = rp[v0], f0 = rp[v0 + 1];
    float2 acc1 = {0.f, 0.f};
    int e1 = 0, f1 = 0;
    if (has1) {
        acc1 = bfpair(Gq[(size_t)v1 * 64 + lane]);
        e1 = f0; f1 = rp[v1 + 1];
    }

    // dual-row batches: 16 independent gathers in flight
    while (e0 + 8 <= f0 && e1 + 8 <= f1) {
        int u0[8], u1[8];
#pragma unroll
        for (int j = 0; j < 8; ++j) u0[j] = col[e0 + j];
#pragma unroll
        for (int j = 0; j < 8; ++j) u1[j] = col[e1 + j];
        u32 q0[8], q1[8];
#pragma unroll
        for (int j = 0; j < 8; ++j) q0[j] = Gq[(size_t)u0[j] * 64 + lane];
#pragma unroll
        for (int j = 0; j < 8; ++j) q1[j] = Gq[(size_t)u1[j] * 64 + lane];
#pragma unroll
        for (int j = 0; j < 8; ++j) {
            float2 a = bfpair(q0[j]);
            acc0.x += a.x; acc0.y += a.y;
        }
#pragma unroll
        for (int j = 0; j < 8; ++j) {
            float2 a = bfpair(q1[j]);
            acc1.x += a.x; acc1.y += a.y;
        }
        e0 += 8; e1 += 8;
    }
    // single-row batches
    for (; e0 + 8 <= f0; e0 += 8) {
        int u[8];
#pragma unroll
        for (int j = 0; j < 8; ++j) u[j] = col[e0 + j];
        u32 q[8];
#pragma unroll
        for (int j = 0; j < 8; ++j) q[j] = Gq[(size_t)u[j] * 64 + lane];
#pragma unroll
        for (int j = 0; j < 8; ++j) {
            float2 a = bfpair(q[j]);
            acc0.x += a.x; acc0.y += a.y;
        }
    }
    for (; e1 + 8 <= f1; e1 += 8) {
        int u[8];
#pragma unroll
        for (int j = 0; j < 8; ++j) u[j] = col[e1 + j];
        u32 q[8];
#pragma unroll
        for (int j = 0; j < 8; ++j) q[j] = Gq[(size_t)u[j] * 64 + lane];
#pragma unroll
        for (int j = 0; j < 8; ++j) {
            float2 a = bfpair(q[j]);
            acc1.x += a.x; acc1.y += a.y;
        }
    }
    for (; e0 < f0; ++e0) {
        float2 a = bfpair(Gq[(size_t)col[e0] * 64 + lane]);
        acc0.x += a.x; acc0.y += a.y;
    }
    for (; e1 < f1; ++e1) {
        float2 a = bfpair(Gq[(size_t)col[e1] * 64 + lane]);
        acc1.x += a.x; acc1.y += a.y;
    }

    // epilogues
    {
        float s = dinv[v0];
        float rx = acc0.x * s, ry = acc0.y * s;
        if (HAS_BIAS) { rx += bias[2 * lane]; ry += bias[2 * lane + 1]; }
        if (RELU) { rx = fmaxf(rx, 0.f); ry = fmaxf(ry, 0.f); }
        if (OUT_BF16) ((u32*)Y)[(size_t)v0 * 64 + lane] = packbf2(rx, ry);
        else {
            float2 o2; o2.x = rx; o2.y = ry;
            *(float2*)((float*)Y + (size_t)v0 * 128 + 2 * lane) = o2;
        }
    }
    if (has1) {
        float s = dinv[v1];
        float rx = acc1.x * s, ry = acc1.y * s;
        if (HAS_BIAS) { rx += bias[2 * lane]; ry += bias[2 * lane + 1]; }
        if (RELU) { rx = fmaxf(rx, 0.f); ry = fmaxf(ry, 0.f); }
        if (OUT_BF16) ((u32*)Y)[(size_t)v1 * 64 + lane] = packbf2(rx, ry);
        else {
            float2 o2; o2.x = rx; o2.y = ry;
            *(float2*)((float*)Y + (size_t)v1 * 128 + 2 * lane) = o2;
        }
    }
}

// ---------------------------------------------------------------------------
// SpMM-64 (bf16 in): lane <-> channel. Two nodes per wave. Optional bf16 out.
// ---------------------------------------------------------------------------
template <bool OUT_BF16, bool RELU, bool HAS_BIAS, bool PRESCALE>
__global__ __launch_bounds__(256) void k_spmm64(const u16* __restrict__ G16,
                                                const int* __restrict__ rp,
                                                const int* __restrict__ col,
                                                const float* __restrict__ dinv,
                                                const float* __restrict__ bias,
                                                void* __restrict__ Y, int N) {
    int wid = threadIdx.x >> 6, lane = threadIdx.x & 63;
    int v0 = blockIdx.x * 8 + wid * 2;
    if (v0 >= N) return;
    int v1 = v0 + 1;
    bool has1 = (v1 < N);

    float acc0 = bf2f(G16[(size_t)v0 * 64 + lane]);
    int e0 = rp[v0], f0 = rp[v0 + 1];
    float acc1 = 0.f;
    int e1 = 0, f1 = 0;
    if (has1) {
        acc1 = bf2f(G16[(size_t)v1 * 64 + lane]);
        e1 = f0; f1 = rp[v1 + 1];
    }

    while (e0 + 8 <= f0 && e1 + 8 <= f1) {
        int u0[8], u1[8];
#pragma unroll
        for (int j = 0; j < 8; ++j) u0[j] = col[e0 + j];
#pragma unroll
        for (int j = 0; j < 8; ++j) u1[j] = col[e1 + j];
        u16 g0[8], g1[8];
#pragma unroll
        for (int j = 0; j < 8; ++j) g0[j] = G16[(size_t)u0[j] * 64 + lane];
#pragma unroll
        for (int j = 0; j < 8; ++j) g1[j] = G16[(size_t)u1[j] * 64 + lane];
        acc0 += ((bf2f(g0[0]) + bf2f(g0[1])) + (bf2f(g0[2]) + bf2f(g0[3]))) +
                ((bf2f(g0[4]) + bf2f(g0[5])) + (bf2f(g0[6]) + bf2f(g0[7])));
        acc1 += ((bf2f(g1[0]) + bf2f(g1[1])) + (bf2f(g1[2]) + bf2f(g1[3]))) +
                ((bf2f(g1[4]) + bf2f(g1[5])) + (bf2f(g1[6]) + bf2f(g1[7])));
        e0 += 8; e1 += 8;
    }
    for (; e0 + 8 <= f0; e0 += 8) {
        int u[8];
#pragma unroll
        for (int j = 0; j < 8; ++j) u[j] = col[e0 + j];
        u16 g[8];
#pragma unroll
        for (int j = 0; j < 8; ++j) g[j] = G16[(size_t)u[j] * 64 + lane];
        acc0 += ((bf2f(g[0]) + bf2f(g[1])) + (bf2f(g[2]) + bf2f(g[3]))) +
                ((bf2f(g[4]) + bf2f(g[5])) + (bf2f(g[6]) + bf2f(g[7])));
    }
    for (; e1 + 8 <= f1; e1 += 8) {
        int u[8];
#pragma unroll
        for (int j = 0; j < 8; ++j) u[j] = col[e1 + j];
        u16 g[8];
#pragma unroll
        for (int j = 0; j < 8; ++j) g[j] = G16[(size_t)u[j] * 64 + lane];
        acc1 += ((bf2f(g[0]) + bf2f(g[1])) + (bf2f(g[2]) + bf2f(g[3]))) +
                ((bf2f(g[4]) + bf2f(g[5])) + (bf2f(g[6]) + bf2f(g[7])));
    }
    for (; e0 < f0; ++e0) acc0 += bf2f(G16[(size_t)col[e0] * 64 + lane]);
    for (; e1 < f1; ++e1) acc1 += bf2f(G16[(size_t)col[e1] * 64 + lane]);

    {
        float s = dinv[v0];
        float r = acc0 * s;
        if (HAS_BIAS) r += bias[lane];
        if (RELU) r = fmaxf(r, 0.f);
        if (PRESCALE) r *= s;
        if (OUT_BF16) ((u16*)Y)[(size_t)v0 * 64 + lane] = f2bf_rne(r);
        else          ((float*)Y)[(size_t)v0 * 64 + lane] = r;
    }
    if (has1) {
        float s = dinv[v1];
        float r = acc1 * s;
        if (HAS_BIAS) r += bias[lane];
        if (RELU) r = fmaxf(r, 0.f);
        if (PRESCALE) r *= s;
        if (OUT_BF16) ((u16*)Y)[(size_t)v1 * 64 + lane] = f2bf_rne(r);
        else          ((float*)Y)[(size_t)v1 * 64 + lane] = r;
    }
}

// ---------------------------------------------------------------------------
extern "C" void kernel_launch(void* const* d_in, const int* in_sizes, int n_in,
                              void* d_out, int out_size, void* d_ws, size_t ws_size,
                              hipStream_t stream) {
    const float* x  = (const float*)d_in[0];
    const void*  ei = d_in[1];
    const float* W1 = (const float*)d_in[2];
    const float* b1 = (const float*)d_in[3];
    const float* W2 = (const float*)d_in[4];
    const float* b2 = (const float*)d_in[5];
    const float* W3 = (const float*)d_in[6];
    const float* b3 = (const float*)d_in[7];
    const float* W4 = (const float*)d_in[8];
    const float* b4 = (const float*)d_in[9];

    const int N = in_sizes[0] / 128;   // 100000
    const int E = in_sizes[1] / 2;     // 1600000

    // workspace carve-up (256B aligned)
    size_t off = 0;
    auto alloc = [&](size_t bytes) -> void* {
        void* p = (char*)d_ws + off;
        off += (bytes + 255) & ~(size_t)255;
        return p;
    };
    u32*   flag    = (u32*)  alloc(4);
    int*   src32   = (int*)  alloc((size_t)E * 4);
    int*   dst32   = (int*)  alloc((size_t)E * 4);   // contiguous with src32
    u32*   deg     = (u32*)  alloc((size_t)N * 4);
    float* dinv    = (float*)alloc((size_t)N * 4);
    int*   row_ptr = (int*)  alloc((size_t)(N + 1) * 4);
    u32*   cnt     = (u32*)  alloc((size_t)N * 4);
    u32*   partial = (u32*)  alloc(256 * 4);
    int*   col     = (int*)  alloc((size_t)E * 4);
    u16*   xb      = (u16*)  alloc((size_t)N * 128 * 2);   // x as bf16
    u16*   Wp1     = (u16*)  alloc(128 * 128 * 2);
    u16*   Wp2     = (u16*)  alloc(64 * 128 * 2);
    u16*   Wp3     = (u16*)  alloc(128 * 64 * 2);
    u16*   Wp4     = (u16*)  alloc(128 * 128 * 2);
    u16*   BUF1    = (u16*)  alloc((size_t)N * 128 * 2);   // G1 / aggz / G4
    u16*   BUF2    = (u16*)  alloc((size_t)N * 128 * 2);   // h1 / h3
    u16*   BUF3    = (u16*)  alloc((size_t)N * 64 * 2);    // G2
    u16*   Zbf     = (u16*)d_out;   // zh (N x 64 bf16) borrows d_out; dead before final write

    const int n2 = 2 * E;
    const int NB = (N + 1023) / 1024;

    // graph preprocessing
    k_detect<<<1, 256, 0, stream>>>((const int*)ei, n2, flag);
    k_convert<<<(n2 + 255) / 256, 256, 0, stream>>>(ei, n2, flag, src32);  // [0..E)=src, [E..2E)=dst
    int* dstp = src32 + E;
    k_init<<<(N + 255) / 256, 256, 0, stream>>>(deg, cnt, N);
    k_count<<<1024, 256, 0, stream>>>(dstp, deg, E, N);
    k_dinv<<<(N + 255) / 256, 256, 0, stream>>>(deg, dinv, N);
    k_scan_a<<<NB, 256, 0, stream>>>(deg, partial, N);
    k_scan_b<<<1, 128, 0, stream>>>(partial, NB, row_ptr, N);
    k_scan_c<<<NB, 256, 0, stream>>>(deg, partial, row_ptr, N);
    k_fill<<<1024, 256, 0, stream>>>(src32, dstp, row_ptr, cnt, col, E, N);
    (void)dst32;

    // bf16 conversions / weight fragment packing
    k_cvt<<<1024, 256, 0, stream>>>(x, xb, N * 128);
    k_wpack<128, 128><<<(128 * 128 + 255) / 256, 256, 0, stream>>>(W1, Wp1);
    k_wpack<128, 64><<<(128 * 64 + 255) / 256, 256, 0, stream>>>(W2, Wp2);
    k_wpack<64, 128><<<(64 * 128 + 255) / 256, 256, 0, stream>>>(W3, Wp3);
    k_wpack<128, 128><<<(128 * 128 + 255) / 256, 256, 0, stream>>>(W4, Wp4);

    const int gM = (N + 63) / 64;    // mgemm grid
    const int gS = (N + 7) / 8;      // spmm grid (2 nodes/wave, 4 waves/block)

    // Layer 1: G1 = (x@W1ᵀ)·dinv ; h1 = relu(agg + b1) -> bf16
    k_mgemm<128, 128, 0><<<gM, 256, 0, stream>>>(xb, Wp1, dinv, BUF1, N);
    k_spmm128<true, true, true><<<gS, 256, 0, stream>>>((const u32*)BUF1, row_ptr, col, dinv, b1, BUF2, N);

    // Layer 2: G2 = (h1@W2ᵀ)·dinv ; zh = dinv·(agg + b2) -> bf16 (in d_out)
    k_mgemm<128, 64, 0><<<gM, 256, 0, stream>>>(BUF2, Wp2, dinv, BUF3, N);
    k_spmm64<true, false, true, true><<<gS, 256, 0, stream>>>(BUF3, row_ptr, col, dinv, b2, Zbf, N);

    // Layer 3 (reordered): aggz = dinv·(zh + sum zh) -> bf16 ; h3 = relu(aggz@W3ᵀ + b3) -> bf16
    k_spmm64<true, false, false, false><<<gS, 256, 0, stream>>>(Zbf, row_ptr, col, dinv, b2, BUF1, N);
    k_mgemm<64, 128, 1><<<gM, 256, 0, stream>>>(BUF1, Wp3, b3, BUF2, N);

    // Layer 4: G4 = (h3@W4ᵀ)·dinv ; out = agg·dinv + b4 -> f32 d_out
    k_mgemm<128, 128, 0><<<gM, 256, 0, stream>>>(BUF2, Wp4, dinv, BUF1, N);
    k_spmm128<false, false, true><<<gS, 256, 0, stream>>>((const u32*)BUF1, row_ptr, col, dinv, b4, d_out, N);
}

// Round 8
// 496.426 us; speedup vs baseline: 2.4904x; 1.0278x over previous
//
#include <hip/hip_runtime.h>

typedef unsigned int u32;
typedef unsigned short u16;
typedef short bf16x4 __attribute__((ext_vector_type(4)));
typedef short bf16x8 __attribute__((ext_vector_type(8)));
typedef float f32x4 __attribute__((ext_vector_type(4)));

// bf16 helpers: round-to-nearest-even pack, cheap unpack
__device__ inline u16 f2bf_rne(float f) {
    u32 b = __float_as_uint(f);
    return (u16)((b + 0x7FFFu + ((b >> 16) & 1u)) >> 16);
}
__device__ inline u32 packbf2(float lo, float hi) {
    return (u32)f2bf_rne(lo) | ((u32)f2bf_rne(hi) << 16);
}
__device__ inline float bf2f(u16 h) { return __uint_as_float((u32)h << 16); }
__device__ inline float2 bfpair(u32 q) {
    float2 f;
    f.x = __uint_as_float(q << 16);
    f.y = __uint_as_float(q & 0xFFFF0000u);
    return f;
}

// ---------------------------------------------------------------------------
// Edge-index dtype detection (int64 vs int32 buffer)
// ---------------------------------------------------------------------------
__global__ void k_detect(const int* __restrict__ p, int n_int32, u32* __restrict__ flag) {
    __shared__ int s[256];
    int tid = threadIdx.x;
    int acc = 0;
    int limit = n_int32 < 2048 ? n_int32 : 2048;
    for (int i = 1 + 2 * tid; i < limit; i += 512) acc |= p[i];
    s[tid] = acc;
    __syncthreads();
    for (int o = 128; o > 0; o >>= 1) {
        if (tid < o) s[tid] |= s[tid + o];
        __syncthreads();
    }
    if (tid == 0) *flag = (s[0] == 0) ? 1u : 0u;
}

__global__ void k_convert(const void* __restrict__ p, int n, const u32* __restrict__ flag,
                          int* __restrict__ out) {
    int i = blockIdx.x * blockDim.x + threadIdx.x;
    if (i >= n) return;
    if (*flag) out[i] = (int)((const long long*)p)[i];
    else       out[i] = ((const int*)p)[i];
}

// Pack W (f32 [COUT][CIN]) into mfma B-fragment register order (bf16):
// Wpk[((fi*KS + ks)*64 + lane)*8 + e] = bf16(W[fi*16+l15][ks*32 + 4*l4 + (e&3) + 16*(e>>2)])
// where lane = l4*16 + l15. A wave loads fragment (fi,ks) as one coalesced
// 16B/lane (1KB/wave) global read.
template <int CIN, int COUT>
__global__ void k_wpack(const float* __restrict__ W, u16* __restrict__ Wpk) {
    int i = blockIdx.x * 256 + threadIdx.x;
    if (i >= CIN * COUT) return;
    int o = i / CIN, k = i % CIN;
    int fi = o >> 4, l15 = o & 15;
    int ks = k >> 5, w = k & 31;
    int h = w >> 4, l4 = (w & 15) >> 2, off = w & 3;
    int lane = l4 * 16 + l15;
    int e = h * 4 + off;
    constexpr int KS = CIN / 32;
    Wpk[(size_t)(((fi * KS + ks) * 64 + lane) * 8 + e)] = f2bf_rne(W[i]);
}

// ---------------------------------------------------------------------------
// Degree / dinv / CSR build
// ---------------------------------------------------------------------------
__global__ void k_init(u32* __restrict__ deg, u32* __restrict__ cnt, int N) {
    int i = blockIdx.x * blockDim.x + threadIdx.x;
    if (i < N) { deg[i] = 1u; cnt[i] = 0u; }  // deg starts at 1 (self-loop)
}

// XCD-range-partitioned degree count (keeps atomic lines in one XCD's L2)
__global__ __launch_bounds__(256) void k_count(const int* __restrict__ dst,
                                               u32* __restrict__ deg, int E, int N) {
    int xcd = blockIdx.x & 7;
    int sub = blockIdx.x >> 3;
    int nsub = gridDim.x >> 3;
    int lo = (int)((long long)N * xcd >> 3);
    int hi = (int)((long long)N * (xcd + 1) >> 3);
    for (int e = sub * 256 + threadIdx.x; e < E; e += nsub * 256) {
        int d = dst[e];
        if (d >= lo && d < hi) atomicAdd(&deg[d], 1u);
    }
}

__global__ void k_dinv(const u32* __restrict__ deg, float* __restrict__ dinv, int N) {
    int i = blockIdx.x * blockDim.x + threadIdx.x;
    if (i < N) dinv[i] = rsqrtf((float)deg[i]);
}

// 3-phase exclusive scan of (deg[v]-1) -> row_ptr
__global__ void k_scan_a(const u32* __restrict__ deg, u32* __restrict__ partial, int N) {
    __shared__ u32 s[256];
    int tid = threadIdx.x;
    int base = blockIdx.x * 1024 + tid * 4;
    u32 sum = 0;
#pragma unroll
    for (int j = 0; j < 4; ++j) {
        int v = base + j;
        sum += (v < N) ? (deg[v] - 1u) : 0u;
    }
    s[tid] = sum;
    __syncthreads();
    for (int o = 128; o > 0; o >>= 1) {
        if (tid < o) s[tid] += s[tid + o];
        __syncthreads();
    }
    if (tid == 0) partial[blockIdx.x] = s[0];
}

__global__ void k_scan_b(u32* __restrict__ partial, int NB, int* __restrict__ row_ptr, int N) {
    __shared__ u32 s[128];
    int tid = threadIdx.x;
    u32 v = (tid < NB) ? partial[tid] : 0u;
    s[tid] = v;
    __syncthreads();
    for (int off = 1; off < 128; off <<= 1) {
        u32 t = (tid >= off) ? s[tid - off] : 0u;
        __syncthreads();
        s[tid] += t;
        __syncthreads();
    }
    if (tid < NB) partial[tid] = s[tid] - v;
    if (tid == 127) row_ptr[N] = (int)s[127];
}

__global__ void k_scan_c(const u32* __restrict__ deg, const u32* __restrict__ partial,
                         int* __restrict__ row_ptr, int N) {
    __shared__ u32 s[256];
    int tid = threadIdx.x;
    int base = blockIdx.x * 1024 + tid * 4;
    u32 vals[4];
    u32 sum = 0;
#pragma unroll
    for (int j = 0; j < 4; ++j) {
        int v = base + j;
        vals[j] = (v < N) ? (deg[v] - 1u) : 0u;
        sum += vals[j];
    }
    s[tid] = sum;
    __syncthreads();
    for (int off = 1; off < 256; off <<= 1) {
        u32 t = (tid >= off) ? s[tid - off] : 0u;
        __syncthreads();
        s[tid] += t;
        __syncthreads();
    }
    u32 run = s[tid] - sum + partial[blockIdx.x];
#pragma unroll
    for (int j = 0; j < 4; ++j) {
        int v = base + j;
        if (v < N) row_ptr[v] = (int)run;
        run += vals[j];
    }
}

// XCD-range-partitioned CSR fill
__global__ __launch_bounds__(256) void k_fill(const int* __restrict__ src,
                                              const int* __restrict__ dst,
                                              const int* __restrict__ row_ptr,
                                              u32* __restrict__ cnt,
                                              int* __restrict__ col, int E, int N) {
    int xcd = blockIdx.x & 7;
    int sub = blockIdx.x >> 3;
    int nsub = gridDim.x >> 3;
    int lo = (int)((long long)N * xcd >> 3);
    int hi = (int)((long long)N * (xcd + 1) >> 3);
    for (int e = sub * 256 + threadIdx.x; e < E; e += nsub * 256) {
        int d = dst[e];
        if (d >= lo && d < hi) {
            int pos = row_ptr[d] + (int)atomicAdd(&cnt[d], 1u);
            col[pos] = src[e];
        }
    }
}

// ---------------------------------------------------------------------------
// MFMA GEMM v3: Gout[row][o] = epi( sum_k X[row][k]*W[o][k] ), bf16 out
//   MODE 0: epi = acc * dinv[row]   (aux = dinv)
//   MODE 1: epi = relu(acc + bias)  (aux = bias)
// Block = 512 thr = 8 waves = 4 row-groups x 2 col-groups; 64 rows/block.
// Each wave: 16 rows x COUT/2 cols -> NT = COUT/32 col-tiles, wfrag in VGPR
// (NT*KS*4 regs), X tile in LDS. IN_F32: stage-convert f32 input inline.
// ---------------------------------------------------------------------------
template <int CIN, int COUT, int MODE, bool IN_F32>
__global__ __launch_bounds__(512, 2) void k_mgemm(const void* __restrict__ Xv,
                                                  const u16* __restrict__ Wpk,
                                                  const float* __restrict__ aux,
                                                  u16* __restrict__ Gout, int N) {
    constexpr int PITCH = CIN + 8;        // u16 units
    constexpr int KS = CIN / 32;          // mfma k-steps
    constexpr int NT = COUT / 32;         // col-tiles per wave (per col-group)
    __shared__ __align__(16) u16 sX[64 * PITCH];

    int tid = threadIdx.x, wid = tid >> 6, lane = tid & 63;
    int l15 = lane & 15, l4 = lane >> 4;
    int rg = wid >> 1;                    // row group 0..3
    int cg = wid & 1;                     // col group 0..1
    int rowbase = blockIdx.x * 64;

    // W fragments -> registers (L2-hot, coalesced 16B/lane)
    bf16x8 wfrag[NT][KS];
#pragma unroll
    for (int nt = 0; nt < NT; ++nt) {
        int fi = cg * NT + nt;
#pragma unroll
        for (int ks = 0; ks < KS; ++ks)
            wfrag[nt][ks] = *(const bf16x8*)&Wpk[(size_t)(((fi * KS + ks) * 64 + lane) * 8)];
    }

    // stage X tile (64 rows x CIN), optional f32->bf16 inline convert
    if (IN_F32) {
        const float* Xf = (const float*)Xv;
        for (int i = tid * 8; i < 64 * CIN; i += 512 * 8) {
            int r = i / CIN, k = i % CIN;
            int row = rowbase + r;
            if (row >= N) row = N - 1;
            const float4* xp = (const float4*)(Xf + (size_t)row * CIN + k);
            float4 a = xp[0], b = xp[1];
            uint4 pk;
            pk.x = packbf2(a.x, a.y);
            pk.y = packbf2(a.z, a.w);
            pk.z = packbf2(b.x, b.y);
            pk.w = packbf2(b.z, b.w);
            *(uint4*)&sX[r * PITCH + k] = pk;
        }
    } else {
        const u16* Xb = (const u16*)Xv;
        for (int i = tid * 8; i < 64 * CIN; i += 512 * 8) {
            int r = i / CIN, k = i % CIN;
            int row = rowbase + r;
            if (row >= N) row = N - 1;
            *(bf16x8*)&sX[r * PITCH + k] = *(const bf16x8*)&Xb[(size_t)row * CIN + k];
        }
    }
    __syncthreads();

    f32x4 acc[NT];
#pragma unroll
    for (int nt = 0; nt < NT; ++nt) acc[nt] = (f32x4){0.f, 0.f, 0.f, 0.f};

    const u16* xrow = &sX[(rg * 16 + l15) * PITCH + 4 * l4];

#pragma unroll
    for (int ks = 0; ks < KS; ++ks) {
        bf16x4 a0 = *(const bf16x4*)(xrow + ks * 32);
        bf16x4 a1 = *(const bf16x4*)(xrow + ks * 32 + 16);
        bf16x8 av = __builtin_shufflevector(a0, a1, 0, 1, 2, 3, 4, 5, 6, 7);
#pragma unroll
        for (int nt = 0; nt < NT; ++nt)
            acc[nt] = __builtin_amdgcn_mfma_f32_16x16x32_bf16(av, wfrag[nt][ks], acc[nt], 0, 0, 0);
    }

    // epilogue: lane reg i -> row rowbase + rg*16 + 4*l4 + i, col cg*(COUT/2) + nt*16 + l15
    float bv[NT];
    if (MODE == 1) {
#pragma unroll
        for (int nt = 0; nt < NT; ++nt) bv[nt] = aux[cg * (COUT / 2) + nt * 16 + l15];
    }
#pragma unroll
    for (int i = 0; i < 4; ++i) {
        int row = rowbase + rg * 16 + 4 * l4 + i;
        if (row < N) {
            float s = (MODE == 0) ? aux[row] : 0.f;
#pragma unroll
            for (int nt = 0; nt < NT; ++nt) {
                float a = acc[nt][i];
                float o = (MODE == 0) ? a * s : fmaxf(a + bv[nt], 0.f);
                Gout[(size_t)row * COUT + cg * (COUT / 2) + nt * 16 + l15] = f2bf_rne(o);
            }
        }
    }
}

// ---------------------------------------------------------------------------
// SpMM-128 (bf16 in): acc = G[v] + sum G[col[e]]; r = acc*dinv[v] (+bias, relu)
// Lane holds channel pair (2*lane, 2*lane+1) packed in one u32.
// TWO nodes per wave, dual 8-batches interleaved -> 16 gathers in flight.
// ---------------------------------------------------------------------------
template <bool OUT_BF16, bool RELU, bool HAS_BIAS>
__global__ __launch_bounds__(256) void k_spmm128(const u32* __restrict__ Gq,
                                                 const int* __restrict__ rp,
                                                 const int* __restrict__ col,
                                                 const float* __restrict__ dinv,
                                                 const float* __restrict__ bias,
                                                 void* __restrict__ Y, int N) {
    int wid = threadIdx.x >> 6, lane = threadIdx.x & 63;
    int v0 = blockIdx.x * 8 + wid * 2;
    if (v0 >= N) return;
    int v1 = v0 + 1;
    bool has1 = (v1 < N);

    float2 acc0 = bfpair(Gq[(size_t)v0 * 64 + lane]);
    int e0 = rp[v0], f0 = rp[v0 + 1];
    float2 acc1 = {0.f, 0.f};
    int e1 = 0, f1 = 0;
    if (has1) {
        acc1 = bfpair(Gq[(size_t)v1 * 64 + lane]);
        e1 = f0; f1 = rp[v1 + 1];
    }

    // dual-row batches: 16 independent gathers in flight
    while (e0 + 8 <= f0 && e1 + 8 <= f1) {
        int u0[8], u1[8];
#pragma unroll
        for (int j = 0; j < 8; ++j) u0[j] = col[e0 + j];
#pragma unroll
        for (int j = 0; j < 8; ++j) u1[j] = col[e1 + j];
        u32 q0[8], q1[8];
#pragma unroll
        for (int j = 0; j < 8; ++j) q0[j] = Gq[(size_t)u0[j] * 64 + lane];
#pragma unroll
        for (int j = 0; j < 8; ++j) q1[j] = Gq[(size_t)u1[j] * 64 + lane];
#pragma unroll
        for (int j = 0; j < 8; ++j) {
            float2 a = bfpair(q0[j]);
            acc0.x += a.x; acc0.y += a.y;
        }
#pragma unroll
        for (int j = 0; j < 8; ++j) {
            float2 a = bfpair(q1[j]);
            acc1.x += a.x; acc1.y += a.y;
        }
        e0 += 8; e1 += 8;
    }
    // single-row batches
    for (; e0 + 8 <= f0; e0 += 8) {
        int u[8];
#pragma unroll
        for (int j = 0; j < 8; ++j) u[j] = col[e0 + j];
        u32 q[8];
#pragma unroll
        for (int j = 0; j < 8; ++j) q[j] = Gq[(size_t)u[j] * 64 + lane];
#pragma unroll
        for (int j = 0; j < 8; ++j) {
            float2 a = bfpair(q[j]);
            acc0.x += a.x; acc0.y += a.y;
        }
    }
    for (; e1 + 8 <= f1; e1 += 8) {
        int u[8];
#pragma unroll
        for (int j = 0; j < 8; ++j) u[j] = col[e1 + j];
        u32 q[8];
#pragma unroll
        for (int j = 0; j < 8; ++j) q[j] = Gq[(size_t)u[j] * 64 + lane];
#pragma unroll
        for (int j = 0; j < 8; ++j) {
            float2 a = bfpair(q[j]);
            acc1.x += a.x; acc1.y += a.y;
        }
    }
    for (; e0 < f0; ++e0) {
        float2 a = bfpair(Gq[(size_t)col[e0] * 64 + lane]);
        acc0.x += a.x; acc0.y += a.y;
    }
    for (; e1 < f1; ++e1) {
        float2 a = bfpair(Gq[(size_t)col[e1] * 64 + lane]);
        acc1.x += a.x; acc1.y += a.y;
    }

    // epilogues
    {
        float s = dinv[v0];
        float rx = acc0.x * s, ry = acc0.y * s;
        if (HAS_BIAS) { rx += bias[2 * lane]; ry += bias[2 * lane + 1]; }
        if (RELU) { rx = fmaxf(rx, 0.f); ry = fmaxf(ry, 0.f); }
        if (OUT_BF16) ((u32*)Y)[(size_t)v0 * 64 + lane] = packbf2(rx, ry);
        else {
            float2 o2; o2.x = rx; o2.y = ry;
            *(float2*)((float*)Y + (size_t)v0 * 128 + 2 * lane) = o2;
        }
    }
    if (has1) {
        float s = dinv[v1];
        float rx = acc1.x * s, ry = acc1.y * s;
        if (HAS_BIAS) { rx += bias[2 * lane]; ry += bias[2 * lane + 1]; }
        if (RELU) { rx = fmaxf(rx, 0.f); ry = fmaxf(ry, 0.f); }
        if (OUT_BF16) ((u32*)Y)[(size_t)v1 * 64 + lane] = packbf2(rx, ry);
        else {
            float2 o2; o2.x = rx; o2.y = ry;
            *(float2*)((float*)Y + (size_t)v1 * 128 + 2 * lane) = o2;
        }
    }
}

// ---------------------------------------------------------------------------
// SpMM-64 (bf16 in): lane <-> channel. Two nodes per wave. Optional bf16 out.
// ---------------------------------------------------------------------------
template <bool OUT_BF16, bool RELU, bool HAS_BIAS, bool PRESCALE>
__global__ __launch_bounds__(256) void k_spmm64(const u16* __restrict__ G16,
                                                const int* __restrict__ rp,
                                                const int* __restrict__ col,
                                                const float* __restrict__ dinv,
                                                const float* __restrict__ bias,
                                                void* __restrict__ Y, int N) {
    int wid = threadIdx.x >> 6, lane = threadIdx.x & 63;
    int v0 = blockIdx.x * 8 + wid * 2;
    if (v0 >= N) return;
    int v1 = v0 + 1;
    bool has1 = (v1 < N);

    float acc0 = bf2f(G16[(size_t)v0 * 64 + lane]);
    int e0 = rp[v0], f0 = rp[v0 + 1];
    float acc1 = 0.f;
    int e1 = 0, f1 = 0;
    if (has1) {
        acc1 = bf2f(G16[(size_t)v1 * 64 + lane]);
        e1 = f0; f1 = rp[v1 + 1];
    }

    while (e0 + 8 <= f0 && e1 + 8 <= f1) {
        int u0[8], u1[8];
#pragma unroll
        for (int j = 0; j < 8; ++j) u0[j] = col[e0 + j];
#pragma unroll
        for (int j = 0; j < 8; ++j) u1[j] = col[e1 + j];
        u16 g0[8], g1[8];
#pragma unroll
        for (int j = 0; j < 8; ++j) g0[j] = G16[(size_t)u0[j] * 64 + lane];
#pragma unroll
        for (int j = 0; j < 8; ++j) g1[j] = G16[(size_t)u1[j] * 64 + lane];
        acc0 += ((bf2f(g0[0]) + bf2f(g0[1])) + (bf2f(g0[2]) + bf2f(g0[3]))) +
                ((bf2f(g0[4]) + bf2f(g0[5])) + (bf2f(g0[6]) + bf2f(g0[7])));
        acc1 += ((bf2f(g1[0]) + bf2f(g1[1])) + (bf2f(g1[2]) + bf2f(g1[3]))) +
                ((bf2f(g1[4]) + bf2f(g1[5])) + (bf2f(g1[6]) + bf2f(g1[7])));
        e0 += 8; e1 += 8;
    }
    for (; e0 + 8 <= f0; e0 += 8) {
        int u[8];
#pragma unroll
        for (int j = 0; j < 8; ++j) u[j] = col[e0 + j];
        u16 g[8];
#pragma unroll
        for (int j = 0; j < 8; ++j) g[j] = G16[(size_t)u[j] * 64 + lane];
        acc0 += ((bf2f(g[0]) + bf2f(g[1])) + (bf2f(g[2]) + bf2f(g[3]))) +
                ((bf2f(g[4]) + bf2f(g[5])) + (bf2f(g[6]) + bf2f(g[7])));
    }
    for (; e1 + 8 <= f1; e1 += 8) {
        int u[8];
#pragma unroll
        for (int j = 0; j < 8; ++j) u[j] = col[e1 + j];
        u16 g[8];
#pragma unroll
        for (int j = 0; j < 8; ++j) g[j] = G16[(size_t)u[j] * 64 + lane];
        acc1 += ((bf2f(g[0]) + bf2f(g[1])) + (bf2f(g[2]) + bf2f(g[3]))) +
                ((bf2f(g[4]) + bf2f(g[5])) + (bf2f(g[6]) + bf2f(g[7])));
    }
    for (; e0 < f0; ++e0) acc0 += bf2f(G16[(size_t)col[e0] * 64 + lane]);
    for (; e1 < f1; ++e1) acc1 += bf2f(G16[(size_t)col[e1] * 64 + lane]);

    {
        float s = dinv[v0];
        float r = acc0 * s;
        if (HAS_BIAS) r += bias[lane];
        if (RELU) r = fmaxf(r, 0.f);
        if (PRESCALE) r *= s;
        if (OUT_BF16) ((u16*)Y)[(size_t)v0 * 64 + lane] = f2bf_rne(r);
        else          ((float*)Y)[(size_t)v0 * 64 + lane] = r;
    }
    if (has1) {
        float s = dinv[v1];
        float r = acc1 * s;
        if (HAS_BIAS) r += bias[lane];
        if (RELU) r = fmaxf(r, 0.f);
        if (PRESCALE) r *= s;
        if (OUT_BF16) ((u16*)Y)[(size_t)v1 * 64 + lane] = f2bf_rne(r);
        else          ((float*)Y)[(size_t)v1 * 64 + lane] = r;
    }
}

// ---------------------------------------------------------------------------
extern "C" void kernel_launch(void* const* d_in, const int* in_sizes, int n_in,
                              void* d_out, int out_size, void* d_ws, size_t ws_size,
                              hipStream_t stream) {
    const float* x  = (const float*)d_in[0];
    const void*  ei = d_in[1];
    const float* W1 = (const float*)d_in[2];
    const float* b1 = (const float*)d_in[3];
    const float* W2 = (const float*)d_in[4];
    const float* b2 = (const float*)d_in[5];
    const float* W3 = (const float*)d_in[6];
    const float* b3 = (const float*)d_in[7];
    const float* W4 = (const float*)d_in[8];
    const float* b4 = (const float*)d_in[9];

    const int N = in_sizes[0] / 128;   // 100000
    const int E = in_sizes[1] / 2;     // 1600000

    // workspace carve-up (256B aligned)
    size_t off = 0;
    auto alloc = [&](size_t bytes) -> void* {
        void* p = (char*)d_ws + off;
        off += (bytes + 255) & ~(size_t)255;
        return p;
    };
    u32*   flag    = (u32*)  alloc(4);
    int*   src32   = (int*)  alloc((size_t)E * 4);
    int*   dst32   = (int*)  alloc((size_t)E * 4);   // contiguous with src32
    u32*   deg     = (u32*)  alloc((size_t)N * 4);
    float* dinv    = (float*)alloc((size_t)N * 4);
    int*   row_ptr = (int*)  alloc((size_t)(N + 1) * 4);
    u32*   cnt     = (u32*)  alloc((size_t)N * 4);
    u32*   partial = (u32*)  alloc(256 * 4);
    int*   col     = (int*)  alloc((size_t)E * 4);
    u16*   Wp1     = (u16*)  alloc(128 * 128 * 2);
    u16*   Wp2     = (u16*)  alloc(64 * 128 * 2);
    u16*   Wp3     = (u16*)  alloc(128 * 64 * 2);
    u16*   Wp4     = (u16*)  alloc(128 * 128 * 2);
    u16*   BUF1    = (u16*)  alloc((size_t)N * 128 * 2);   // G1 / aggz / G4
    u16*   BUF2    = (u16*)  alloc((size_t)N * 128 * 2);   // h1 / h3
    u16*   BUF3    = (u16*)  alloc((size_t)N * 64 * 2);    // G2
    u16*   Zbf     = (u16*)d_out;   // zh (N x 64 bf16) borrows d_out; dead before final write

    const int n2 = 2 * E;
    const int NB = (N + 1023) / 1024;

    // graph preprocessing
    k_detect<<<1, 256, 0, stream>>>((const int*)ei, n2, flag);
    k_convert<<<(n2 + 255) / 256, 256, 0, stream>>>(ei, n2, flag, src32);  // [0..E)=src, [E..2E)=dst
    int* dstp = src32 + E;
    k_init<<<(N + 255) / 256, 256, 0, stream>>>(deg, cnt, N);
    k_count<<<1024, 256, 0, stream>>>(dstp, deg, E, N);
    k_dinv<<<(N + 255) / 256, 256, 0, stream>>>(deg, dinv, N);
    k_scan_a<<<NB, 256, 0, stream>>>(deg, partial, N);
    k_scan_b<<<1, 128, 0, stream>>>(partial, NB, row_ptr, N);
    k_scan_c<<<NB, 256, 0, stream>>>(deg, partial, row_ptr, N);
    k_fill<<<1024, 256, 0, stream>>>(src32, dstp, row_ptr, cnt, col, E, N);
    (void)dst32;

    // weight fragment packing
    k_wpack<128, 128><<<(128 * 128 + 255) / 256, 256, 0, stream>>>(W1, Wp1);
    k_wpack<128, 64><<<(128 * 64 + 255) / 256, 256, 0, stream>>>(W2, Wp2);
    k_wpack<64, 128><<<(64 * 128 + 255) / 256, 256, 0, stream>>>(W3, Wp3);
    k_wpack<128, 128><<<(128 * 128 + 255) / 256, 256, 0, stream>>>(W4, Wp4);

    const int gM = (N + 63) / 64;    // mgemm grid (512-thread blocks)
    const int gS = (N + 7) / 8;      // spmm grid (2 nodes/wave, 4 waves/block)

    // Layer 1: G1 = (x@W1ᵀ)·dinv (f32 in, inline cvt) ; h1 = relu(agg + b1) -> bf16
    k_mgemm<128, 128, 0, true><<<gM, 512, 0, stream>>>(x, Wp1, dinv, BUF1, N);
    k_spmm128<true, true, true><<<gS, 256, 0, stream>>>((const u32*)BUF1, row_ptr, col, dinv, b1, BUF2, N);

    // Layer 2: G2 = (h1@W2ᵀ)·dinv ; zh = dinv·(agg + b2) -> bf16 (in d_out)
    k_mgemm<128, 64, 0, false><<<gM, 512, 0, stream>>>(BUF2, Wp2, dinv, BUF3, N);
    k_spmm64<true, false, true, true><<<gS, 256, 0, stream>>>(BUF3, row_ptr, col, dinv, b2, Zbf, N);

    // Layer 3 (reordered): aggz = dinv·(zh + sum zh) -> bf16 ; h3 = relu(aggz@W3ᵀ + b3) -> bf16
    k_spmm64<true, false, false, false><<<gS, 256, 0, stream>>>(Zbf, row_ptr, col, dinv, b2, BUF1, N);
    k_mgemm<64, 128, 1, false><<<gM, 512, 0, stream>>>(BUF1, Wp3, b3, BUF2, N);

    // Layer 4: G4 = (h3@W4ᵀ)·dinv ; out = agg·dinv + b4 -> f32 d_out
    k_mgemm<128, 128, 0, false><<<gM, 512, 0, stream>>>(BUF2, Wp4, dinv, BUF1, N);
    k_spmm128<false, false, true><<<gS, 256, 0, stream>>>((const u32*)BUF1, row_ptr, col, dinv, b4, d_out, N);
}

// Round 9
// 490.175 us; speedup vs baseline: 2.5221x; 1.0128x over previous
//
#include <hip/hip_runtime.h>

typedef unsigned int u32;
typedef unsigned short u16;
typedef short bf16x4 __attribute__((ext_vector_type(4)));
typedef short bf16x8 __attribute__((ext_vector_type(8)));
typedef float f32x4 __attribute__((ext_vector_type(4)));

// bf16 helpers: round-to-nearest-even pack, cheap unpack
__device__ inline u16 f2bf_rne(float f) {
    u32 b = __float_as_uint(f);
    return (u16)((b + 0x7FFFu + ((b >> 16) & 1u)) >> 16);
}
__device__ inline u32 packbf2(float lo, float hi) {
    return (u32)f2bf_rne(lo) | ((u32)f2bf_rne(hi) << 16);
}
__device__ inline float bf2f(u16 h) { return __uint_as_float((u32)h << 16); }
__device__ inline float2 bfpair(u32 q) {
    float2 f;
    f.x = __uint_as_float(q << 16);
    f.y = __uint_as_float(q & 0xFFFF0000u);
    return f;
}

// ---------------------------------------------------------------------------
// Edge-index dtype detection (int64 vs int32 buffer)
// ---------------------------------------------------------------------------
__global__ void k_detect(const int* __restrict__ p, int n_int32, u32* __restrict__ flag) {
    __shared__ int s[256];
    int tid = threadIdx.x;
    int acc = 0;
    int limit = n_int32 < 2048 ? n_int32 : 2048;
    for (int i = 1 + 2 * tid; i < limit; i += 512) acc |= p[i];
    s[tid] = acc;
    __syncthreads();
    for (int o = 128; o > 0; o >>= 1) {
        if (tid < o) s[tid] |= s[tid + o];
        __syncthreads();
    }
    if (tid == 0) *flag = (s[0] == 0) ? 1u : 0u;
}

__global__ void k_convert(const void* __restrict__ p, int n, const u32* __restrict__ flag,
                          int* __restrict__ out) {
    int i = blockIdx.x * blockDim.x + threadIdx.x;
    if (i >= n) return;
    if (*flag) out[i] = (int)((const long long*)p)[i];
    else       out[i] = ((const int*)p)[i];
}

// Pack W (f32 [COUT][CIN]) into mfma B-fragment register order (bf16):
// Wpk[((fi*KS + ks)*64 + lane)*8 + e] = bf16(W[fi*16+l15][ks*32 + 4*l4 + (e&3) + 16*(e>>2)])
// where lane = l4*16 + l15. A wave loads fragment (fi,ks) as one coalesced
// 16B/lane (1KB/wave) global read.
template <int CIN, int COUT>
__global__ void k_wpack(const float* __restrict__ W, u16* __restrict__ Wpk) {
    int i = blockIdx.x * 256 + threadIdx.x;
    if (i >= CIN * COUT) return;
    int o = i / CIN, k = i % CIN;
    int fi = o >> 4, l15 = o & 15;
    int ks = k >> 5, w = k & 31;
    int h = w >> 4, l4 = (w & 15) >> 2, off = w & 3;
    int lane = l4 * 16 + l15;
    int e = h * 4 + off;
    constexpr int KS = CIN / 32;
    Wpk[(size_t)(((fi * KS + ks) * 64 + lane) * 8 + e)] = f2bf_rne(W[i]);
}

// ---------------------------------------------------------------------------
// Degree / dinv / CSR build
// ---------------------------------------------------------------------------
__global__ void k_init(u32* __restrict__ deg, u32* __restrict__ cnt, int N) {
    int i = blockIdx.x * blockDim.x + threadIdx.x;
    if (i < N) { deg[i] = 1u; cnt[i] = 0u; }  // deg starts at 1 (self-loop)
}

// XCD-range-partitioned degree count (keeps atomic lines in one XCD's L2)
__global__ __launch_bounds__(256) void k_count(const int* __restrict__ dst,
                                               u32* __restrict__ deg, int E, int N) {
    int xcd = blockIdx.x & 7;
    int sub = blockIdx.x >> 3;
    int nsub = gridDim.x >> 3;
    int lo = (int)((long long)N * xcd >> 3);
    int hi = (int)((long long)N * (xcd + 1) >> 3);
    for (int e = sub * 256 + threadIdx.x; e < E; e += nsub * 256) {
        int d = dst[e];
        if (d >= lo && d < hi) atomicAdd(&deg[d], 1u);
    }
}

__global__ void k_dinv(const u32* __restrict__ deg, float* __restrict__ dinv, int N) {
    int i = blockIdx.x * blockDim.x + threadIdx.x;
    if (i < N) dinv[i] = rsqrtf((float)deg[i]);
}

// 3-phase exclusive scan of (deg[v]-1) -> row_ptr
__global__ void k_scan_a(const u32* __restrict__ deg, u32* __restrict__ partial, int N) {
    __shared__ u32 s[256];
    int tid = threadIdx.x;
    int base = blockIdx.x * 1024 + tid * 4;
    u32 sum = 0;
#pragma unroll
    for (int j = 0; j < 4; ++j) {
        int v = base + j;
        sum += (v < N) ? (deg[v] - 1u) : 0u;
    }
    s[tid] = sum;
    __syncthreads();
    for (int o = 128; o > 0; o >>= 1) {
        if (tid < o) s[tid] += s[tid + o];
        __syncthreads();
    }
    if (tid == 0) partial[blockIdx.x] = s[0];
}

__global__ void k_scan_b(u32* __restrict__ partial, int NB, int* __restrict__ row_ptr, int N) {
    __shared__ u32 s[128];
    int tid = threadIdx.x;
    u32 v = (tid < NB) ? partial[tid] : 0u;
    s[tid] = v;
    __syncthreads();
    for (int off = 1; off < 128; off <<= 1) {
        u32 t = (tid >= off) ? s[tid - off] : 0u;
        __syncthreads();
        s[tid] += t;
        __syncthreads();
    }
    if (tid < NB) partial[tid] = s[tid] - v;
    if (tid == 127) row_ptr[N] = (int)s[127];
}

__global__ void k_scan_c(const u32* __restrict__ deg, const u32* __restrict__ partial,
                         int* __restrict__ row_ptr, int N) {
    __shared__ u32 s[256];
    int tid = threadIdx.x;
    int base = blockIdx.x * 1024 + tid * 4;
    u32 vals[4];
    u32 sum = 0;
#pragma unroll
    for (int j = 0; j < 4; ++j) {
        int v = base + j;
        vals[j] = (v < N) ? (deg[v] - 1u) : 0u;
        sum += vals[j];
    }
    s[tid] = sum;
    __syncthreads();
    for (int off = 1; off < 256; off <<= 1) {
        u32 t = (tid >= off) ? s[tid - off] : 0u;
        __syncthreads();
        s[tid] += t;
        __syncthreads();
    }
    u32 run = s[tid] - sum + partial[blockIdx.x];
#pragma unroll
    for (int j = 0; j < 4; ++j) {
        int v = base + j;
        if (v < N) row_ptr[v] = (int)run;
        run += vals[j];
    }
}

// XCD-range-partitioned CSR fill
__global__ __launch_bounds__(256) void k_fill(const int* __restrict__ src,
                                              const int* __restrict__ dst,
                                              const int* __restrict__ row_ptr,
                                              u32* __restrict__ cnt,
                                              int* __restrict__ col, int E, int N) {
    int xcd = blockIdx.x & 7;
    int sub = blockIdx.x >> 3;
    int nsub = gridDim.x >> 3;
    int lo = (int)((long long)N * xcd >> 3);
    int hi = (int)((long long)N * (xcd + 1) >> 3);
    for (int e = sub * 256 + threadIdx.x; e < E; e += nsub * 256) {
        int d = dst[e];
        if (d >= lo && d < hi) {
            int pos = row_ptr[d] + (int)atomicAdd(&cnt[d], 1u);
            col[pos] = src[e];
        }
    }
}

// ---------------------------------------------------------------------------
// MFMA GEMM v4 (persistent): Gout[row][o] = epi( sum_k X[row][k]*W[o][k] )
//   MODE 0: epi = acc * dinv[row]   (aux = dinv)
//   MODE 1: epi = relu(acc + bias)  (aux = bias)
// Grid = 512 blocks (2/CU); each block owns a contiguous tile range and keeps
// all W fragments in VGPRs across tiles (loaded ONCE). Per tile: stage X in
// LDS -> MFMA -> acc staged through sE -> coalesced uint4 stores.
// Block = 512 thr = 8 waves = 4 row-groups x 2 col-groups; 64 rows/tile.
// ---------------------------------------------------------------------------
template <int CIN, int COUT, int MODE, bool IN_F32>
__global__ __launch_bounds__(512, 4) void k_mgemm(const void* __restrict__ Xv,
                                                  const u16* __restrict__ Wpk,
                                                  const float* __restrict__ aux,
                                                  u16* __restrict__ Gout, int N,
                                                  int tiles, int tpb) {
    constexpr int PITCH = CIN + 8;        // u16 units
    constexpr int EPITCH = COUT + 8;      // u16 units (272B or 144B rows)
    constexpr int KS = CIN / 32;          // mfma k-steps
    constexpr int NT = COUT / 32;         // col-tiles per wave (per col-group)
    constexpr int CHUNKS = COUT / 8;      // 16B chunks per output row
    __shared__ __align__(16) u16 sX[64 * PITCH];
    __shared__ __align__(16) u16 sE[64 * EPITCH];

    int tid = threadIdx.x, wid = tid >> 6, lane = tid & 63;
    int l15 = lane & 15, l4 = lane >> 4;
    int rg = wid >> 1;                    // row group 0..3
    int cg = wid & 1;                     // col group 0..1

    // W fragments -> registers ONCE (L2-hot, coalesced 16B/lane)
    bf16x8 wfrag[NT][KS];
#pragma unroll
    for (int nt = 0; nt < NT; ++nt) {
        int fi = cg * NT + nt;
#pragma unroll
        for (int ks = 0; ks < KS; ++ks)
            wfrag[nt][ks] = *(const bf16x8*)&Wpk[(size_t)(((fi * KS + ks) * 64 + lane) * 8)];
    }
    float bv[NT];
    if (MODE == 1) {
#pragma unroll
        for (int nt = 0; nt < NT; ++nt) bv[nt] = aux[cg * (COUT / 2) + nt * 16 + l15];
    }

    int t0 = blockIdx.x * tpb;
    int t1 = t0 + tpb; if (t1 > tiles) t1 = tiles;

    for (int t = t0; t < t1; ++t) {
        int rowbase = t * 64;

        // stage X tile (64 rows x CIN), optional f32->bf16 inline convert
        if (IN_F32) {
            const float* Xf = (const float*)Xv;
            for (int i = tid * 8; i < 64 * CIN; i += 512 * 8) {
                int r = i / CIN, k = i % CIN;
                int row = rowbase + r;
                if (row >= N) row = N - 1;
                const float4* xp = (const float4*)(Xf + (size_t)row * CIN + k);
                float4 a = xp[0], b = xp[1];
                uint4 pk;
                pk.x = packbf2(a.x, a.y);
                pk.y = packbf2(a.z, a.w);
                pk.z = packbf2(b.x, b.y);
                pk.w = packbf2(b.z, b.w);
                *(uint4*)&sX[r * PITCH + k] = pk;
            }
        } else {
            const u16* Xb = (const u16*)Xv;
            for (int i = tid * 8; i < 64 * CIN; i += 512 * 8) {
                int r = i / CIN, k = i % CIN;
                int row = rowbase + r;
                if (row >= N) row = N - 1;
                *(bf16x8*)&sX[r * PITCH + k] = *(const bf16x8*)&Xb[(size_t)row * CIN + k];
            }
        }
        __syncthreads();   // (A) sX staged; also fences prev iter's sE reads

        f32x4 acc[NT];
#pragma unroll
        for (int nt = 0; nt < NT; ++nt) acc[nt] = (f32x4){0.f, 0.f, 0.f, 0.f};

        const u16* xrow = &sX[(rg * 16 + l15) * PITCH + 4 * l4];
#pragma unroll
        for (int ks = 0; ks < KS; ++ks) {
            bf16x4 a0 = *(const bf16x4*)(xrow + ks * 32);
            bf16x4 a1 = *(const bf16x4*)(xrow + ks * 32 + 16);
            bf16x8 av = __builtin_shufflevector(a0, a1, 0, 1, 2, 3, 4, 5, 6, 7);
#pragma unroll
            for (int nt = 0; nt < NT; ++nt)
                acc[nt] = __builtin_amdgcn_mfma_f32_16x16x32_bf16(av, wfrag[nt][ks], acc[nt], 0, 0, 0);
        }

        // epilogue phase 1: acc -> sE (LDS scatter, cheap)
#pragma unroll
        for (int i = 0; i < 4; ++i) {
            int rl = rg * 16 + 4 * l4 + i;
            int row = rowbase + rl;
            int rc = row < N ? row : N - 1;
            float s = (MODE == 0) ? aux[rc] : 0.f;
#pragma unroll
            for (int nt = 0; nt < NT; ++nt) {
                float a = acc[nt][i];
                float o = (MODE == 0) ? a * s : fmaxf(a + bv[nt], 0.f);
                sE[rl * EPITCH + cg * (COUT / 2) + nt * 16 + l15] = f2bf_rne(o);
            }
        }
        __syncthreads();   // (B) sE complete; sX reads done

        // epilogue phase 2: coalesced 16B stores
        for (int a = tid; a < 64 * CHUNKS; a += 512) {
            int rl = a / CHUNKS, ch = a % CHUNKS;
            int row = rowbase + rl;
            if (row < N)
                *(uint4*)&Gout[(size_t)row * COUT + ch * 8] =
                    *(const uint4*)&sE[rl * EPITCH + ch * 8];
        }
        // next iter's barrier (A) fences sE reads and sX overwrite
    }
}

// ---------------------------------------------------------------------------
// SpMM-128 (bf16 in): acc = G[v] + sum G[col[e]]; r = acc*dinv[v] (+bias, relu)
// Lane holds channel pair (2*lane, 2*lane+1) packed in one u32.
// TWO nodes per wave, dual 8-batches interleaved -> 16 gathers in flight.
// ---------------------------------------------------------------------------
template <bool OUT_BF16, bool RELU, bool HAS_BIAS>
__global__ __launch_bounds__(256) void k_spmm128(const u32* __restrict__ Gq,
                                                 const int* __restrict__ rp,
                                                 const int* __restrict__ col,
                                                 const float* __restrict__ dinv,
                                                 const float* __restrict__ bias,
                                                 void* __restrict__ Y, int N) {
    int wid = threadIdx.x >> 6, lane = threadIdx.x & 63;
    int v0 = blockIdx.x * 8 + wid * 2;
    if (v0 >= N) return;
    int v1 = v0 + 1;
    bool has1 = (v1 < N);

    float2 acc0 = bfpair(Gq[(size_t)v0 * 64 + lane]);
    int e0 = rp[v0], f0 = rp[v0 + 1];
    float2 acc1 = {0.f, 0.f};
    int e1 = 0, f1 = 0;
    if (has1) {
        acc1 = bfpair(Gq[(size_t)v1 * 64 + lane]);
        e1 = f0; f1 = rp[v1 + 1];
    }

    // dual-row batches: 16 independent gathers in flight
    while (e0 + 8 <= f0 && e1 + 8 <= f1) {
        int u0[8], u1[8];
#pragma unroll
        for (int j = 0; j < 8; ++j) u0[j] = col[e0 + j];
#pragma unroll
        for (int j = 0; j < 8; ++j) u1[j] = col[e1 + j];
        u32 q0[8], q1[8];
#pragma unroll
        for (int j = 0; j < 8; ++j) q0[j] = Gq[(size_t)u0[j] * 64 + lane];
#pragma unroll
        for (int j = 0; j < 8; ++j) q1[j] = Gq[(size_t)u1[j] * 64 + lane];
#pragma unroll
        for (int j = 0; j < 8; ++j) {
            float2 a = bfpair(q0[j]);
            acc0.x += a.x; acc0.y += a.y;
        }
#pragma unroll
        for (int j = 0; j < 8; ++j) {
            float2 a = bfpair(q1[j]);
            acc1.x += a.x; acc1.y += a.y;
        }
        e0 += 8; e1 += 8;
    }
    // single-row batches
    for (; e0 + 8 <= f0; e0 += 8) {
        int u[8];
#pragma unroll
        for (int j = 0; j < 8; ++j) u[j] = col[e0 + j];
        u32 q[8];
#pragma unroll
        for (int j = 0; j < 8; ++j) q[j] = Gq[(size_t)u[j] * 64 + lane];
#pragma unroll
        for (int j = 0; j < 8; ++j) {
            float2 a = bfpair(q[j]);
            acc0.x += a.x; acc0.y += a.y;
        }
    }
    for (; e1 + 8 <= f1; e1 += 8) {
        int u[8];
#pragma unroll
        for (int j = 0; j < 8; ++j) u[j] = col[e1 + j];
        u32 q[8];
#pragma unroll
        for (int j = 0; j < 8; ++j) q[j] = Gq[(size_t)u[j] * 64 + lane];
#pragma unroll
        for (int j = 0; j < 8; ++j) {
            float2 a = bfpair(q[j]);
            acc1.x += a.x; acc1.y += a.y;
        }
    }
    for (; e0 < f0; ++e0) {
        float2 a = bfpair(Gq[(size_t)col[e0] * 64 + lane]);
        acc0.x += a.x; acc0.y += a.y;
    }
    for (; e1 < f1; ++e1) {
        float2 a = bfpair(Gq[(size_t)col[e1] * 64 + lane]);
        acc1.x += a.x; acc1.y += a.y;
    }

    // epilogues
    {
        float s = dinv[v0];
        float rx = acc0.x * s, ry = acc0.y * s;
        if (HAS_BIAS) { rx += bias[2 * lane]; ry += bias[2 * lane + 1]; }
        if (RELU) { rx = fmaxf(rx, 0.f); ry = fmaxf(ry, 0.f); }
        if (OUT_BF16) ((u32*)Y)[(size_t)v0 * 64 + lane] = packbf2(rx, ry);
        else {
            float2 o2; o2.x = rx; o2.y = ry;
            *(float2*)((float*)Y + (size_t)v0 * 128 + 2 * lane) = o2;
        }
    }
    if (has1) {
        float s = dinv[v1];
        float rx = acc1.x * s, ry = acc1.y * s;
        if (HAS_BIAS) { rx += bias[2 * lane]; ry += bias[2 * lane + 1]; }
        if (RELU) { rx = fmaxf(rx, 0.f); ry = fmaxf(ry, 0.f); }
        if (OUT_BF16) ((u32*)Y)[(size_t)v1 * 64 + lane] = packbf2(rx, ry);
        else {
            float2 o2; o2.x = rx; o2.y = ry;
            *(float2*)((float*)Y + (size_t)v1 * 128 + 2 * lane) = o2;
        }
    }
}

// ---------------------------------------------------------------------------
// SpMM-64 (bf16 in): lane <-> channel. Two nodes per wave. Optional bf16 out.
// ---------------------------------------------------------------------------
template <bool OUT_BF16, bool RELU, bool HAS_BIAS, bool PRESCALE>
__global__ __launch_bounds__(256) void k_spmm64(const u16* __restrict__ G16,
                                                const int* __restrict__ rp,
                                                const int* __restrict__ col,
                                                const float* __restrict__ dinv,
                                                const float* __restrict__ bias,
                                                void* __restrict__ Y, int N) {
    int wid = threadIdx.x >> 6, lane = threadIdx.x & 63;
    int v0 = blockIdx.x * 8 + wid * 2;
    if (v0 >= N) return;
    int v1 = v0 + 1;
    bool has1 = (v1 < N);

    float acc0 = bf2f(G16[(size_t)v0 * 64 + lane]);
    int e0 = rp[v0], f0 = rp[v0 + 1];
    float acc1 = 0.f;
    int e1 = 0, f1 = 0;
    if (has1) {
        acc1 = bf2f(G16[(size_t)v1 * 64 + lane]);
        e1 = f0; f1 = rp[v1 + 1];
    }

    while (e0 + 8 <= f0 && e1 + 8 <= f1) {
        int u0[8], u1[8];
#pragma unroll
        for (int j = 0; j < 8; ++j) u0[j] = col[e0 + j];
#pragma unroll
        for (int j = 0; j < 8; ++j) u1[j] = col[e1 + j];
        u16 g0[8], g1[8];
#pragma unroll
        for (int j = 0; j < 8; ++j) g0[j] = G16[(size_t)u0[j] * 64 + lane];
#pragma unroll
        for (int j = 0; j < 8; ++j) g1[j] = G16[(size_t)u1[j] * 64 + lane];
        acc0 += ((bf2f(g0[0]) + bf2f(g0[1])) + (bf2f(g0[2]) + bf2f(g0[3]))) +
                ((bf2f(g0[4]) + bf2f(g0[5])) + (bf2f(g0[6]) + bf2f(g0[7])));
        acc1 += ((bf2f(g1[0]) + bf2f(g1[1])) + (bf2f(g1[2]) + bf2f(g1[3]))) +
                ((bf2f(g1[4]) + bf2f(g1[5])) + (bf2f(g1[6]) + bf2f(g1[7])));
        e0 += 8; e1 += 8;
    }
    for (; e0 + 8 <= f0; e0 += 8) {
        int u[8];
#pragma unroll
        for (int j = 0; j < 8; ++j) u[j] = col[e0 + j];
        u16 g[8];
#pragma unroll
        for (int j = 0; j < 8; ++j) g[j] = G16[(size_t)u[j] * 64 + lane];
        acc0 += ((bf2f(g[0]) + bf2f(g[1])) + (bf2f(g[2]) + bf2f(g[3]))) +
                ((bf2f(g[4]) + bf2f(g[5])) + (bf2f(g[6]) + bf2f(g[7])));
    }
    for (; e1 + 8 <= f1; e1 += 8) {
        int u[8];
#pragma unroll
        for (int j = 0; j < 8; ++j) u[j] = col[e1 + j];
        u16 g[8];
#pragma unroll
        for (int j = 0; j < 8; ++j) g[j] = G16[(size_t)u[j] * 64 + lane];
        acc1 += ((bf2f(g[0]) + bf2f(g[1])) + (bf2f(g[2]) + bf2f(g[3]))) +
                ((bf2f(g[4]) + bf2f(g[5])) + (bf2f(g[6]) + bf2f(g[7])));
    }
    for (; e0 < f0; ++e0) acc0 += bf2f(G16[(size_t)col[e0] * 64 + lane]);
    for (; e1 < f1; ++e1) acc1 += bf2f(G16[(size_t)col[e1] * 64 + lane]);

    {
        float s = dinv[v0];
        float r = acc0 * s;
        if (HAS_BIAS) r += bias[lane];
        if (RELU) r = fmaxf(r, 0.f);
        if (PRESCALE) r *= s;
        if (OUT_BF16) ((u16*)Y)[(size_t)v0 * 64 + lane] = f2bf_rne(r);
        else          ((float*)Y)[(size_t)v0 * 64 + lane] = r;
    }
    if (has1) {
        float s = dinv[v1];
        float r = acc1 * s;
        if (HAS_BIAS) r += bias[lane];
        if (RELU) r = fmaxf(r, 0.f);
        if (PRESCALE) r *= s;
        if (OUT_BF16) ((u16*)Y)[(size_t)v1 * 64 + lane] = f2bf_rne(r);
        else          ((float*)Y)[(size_t)v1 * 64 + lane] = r;
    }
}

// ---------------------------------------------------------------------------
extern "C" void kernel_launch(void* const* d_in, const int* in_sizes, int n_in,
                              void* d_out, int out_size, void* d_ws, size_t ws_size,
                              hipStream_t stream) {
    const float* x  = (const float*)d_in[0];
    const void*  ei = d_in[1];
    const float* W1 = (const float*)d_in[2];
    const float* b1 = (const float*)d_in[3];
    const float* W2 = (const float*)d_in[4];
    const float* b2 = (const float*)d_in[5];
    const float* W3 = (const float*)d_in[6];
    const float* b3 = (const float*)d_in[7];
    const float* W4 = (const float*)d_in[8];
    const float* b4 = (const float*)d_in[9];

    const int N = in_sizes[0] / 128;   // 100000
    const int E = in_sizes[1] / 2;     // 1600000

    // workspace carve-up (256B aligned)
    size_t off = 0;
    auto alloc = [&](size_t bytes) -> void* {
        void* p = (char*)d_ws + off;
        off += (bytes + 255) & ~(size_t)255;
        return p;
    };
    u32*   flag    = (u32*)  alloc(4);
    int*   src32   = (int*)  alloc((size_t)E * 4);
    int*   dst32   = (int*)  alloc((size_t)E * 4);   // contiguous with src32
    u32*   deg     = (u32*)  alloc((size_t)N * 4);
    float* dinv    = (float*)alloc((size_t)N * 4);
    int*   row_ptr = (int*)  alloc((size_t)(N + 1) * 4);
    u32*   cnt     = (u32*)  alloc((size_t)N * 4);
    u32*   partial = (u32*)  alloc(256 * 4);
    int*   col     = (int*)  alloc((size_t)E * 4);
    u16*   Wp1     = (u16*)  alloc(128 * 128 * 2);
    u16*   Wp2     = (u16*)  alloc(64 * 128 * 2);
    u16*   Wp3     = (u16*)  alloc(128 * 64 * 2);
    u16*   Wp4     = (u16*)  alloc(128 * 128 * 2);
    u16*   BUF1    = (u16*)  alloc((size_t)N * 128 * 2);   // G1 / aggz / G4
    u16*   BUF2    = (u16*)  alloc((size_t)N * 128 * 2);   // h1 / h3
    u16*   BUF3    = (u16*)  alloc((size_t)N * 64 * 2);    // G2
    u16*   Zbf     = (u16*)d_out;   // zh (N x 64 bf16) borrows d_out; dead before final write

    const int n2 = 2 * E;
    const int NB = (N + 1023) / 1024;

    // graph preprocessing
    k_detect<<<1, 256, 0, stream>>>((const int*)ei, n2, flag);
    k_convert<<<(n2 + 255) / 256, 256, 0, stream>>>(ei, n2, flag, src32);  // [0..E)=src, [E..2E)=dst
    int* dstp = src32 + E;
    k_init<<<(N + 255) / 256, 256, 0, stream>>>(deg, cnt, N);
    k_count<<<1024, 256, 0, stream>>>(dstp, deg, E, N);
    k_dinv<<<(N + 255) / 256, 256, 0, stream>>>(deg, dinv, N);
    k_scan_a<<<NB, 256, 0, stream>>>(deg, partial, N);
    k_scan_b<<<1, 128, 0, stream>>>(partial, NB, row_ptr, N);
    k_scan_c<<<NB, 256, 0, stream>>>(deg, partial, row_ptr, N);
    k_fill<<<1024, 256, 0, stream>>>(src32, dstp, row_ptr, cnt, col, E, N);
    (void)dst32;

    // weight fragment packing
    k_wpack<128, 128><<<(128 * 128 + 255) / 256, 256, 0, stream>>>(W1, Wp1);
    k_wpack<128, 64><<<(128 * 64 + 255) / 256, 256, 0, stream>>>(W2, Wp2);
    k_wpack<64, 128><<<(64 * 128 + 255) / 256, 256, 0, stream>>>(W3, Wp3);
    k_wpack<128, 128><<<(128 * 128 + 255) / 256, 256, 0, stream>>>(W4, Wp4);

    const int tiles = (N + 63) / 64;
    const int gM = tiles < 512 ? tiles : 512;          // persistent mgemm grid
    const int tpb = (tiles + gM - 1) / gM;             // tiles per block
    const int gS = (N + 7) / 8;      // spmm grid (2 nodes/wave, 4 waves/block)

    // Layer 1: G1 = (x@W1ᵀ)·dinv (f32 in, inline cvt) ; h1 = relu(agg + b1) -> bf16
    k_mgemm<128, 128, 0, true><<<gM, 512, 0, stream>>>(x, Wp1, dinv, BUF1, N, tiles, tpb);
    k_spmm128<true, true, true><<<gS, 256, 0, stream>>>((const u32*)BUF1, row_ptr, col, dinv, b1, BUF2, N);

    // Layer 2: G2 = (h1@W2ᵀ)·dinv ; zh = dinv·(agg + b2) -> bf16 (in d_out)
    k_mgemm<128, 64, 0, false><<<gM, 512, 0, stream>>>(BUF2, Wp2, dinv, BUF3, N, tiles, tpb);
    k_spmm64<true, false, true, true><<<gS, 256, 0, stream>>>(BUF3, row_ptr, col, dinv, b2, Zbf, N);

    // Layer 3 (reordered): aggz = dinv·(zh + sum zh) -> bf16 ; h3 = relu(aggz@W3ᵀ + b3) -> bf16
    k_spmm64<true, false, false, false><<<gS, 256, 0, stream>>>(Zbf, row_ptr, col, dinv, b2, BUF1, N);
    k_mgemm<64, 128, 1, false><<<gM, 512, 0, stream>>>(BUF1, Wp3, b3, BUF2, N, tiles, tpb);

    // Layer 4: G4 = (h3@W4ᵀ)·dinv ; out = agg·dinv + b4 -> f32 d_out
    k_mgemm<128, 128, 0, false><<<gM, 512, 0, stream>>>(BUF2, Wp4, dinv, BUF1, N, tiles, tpb);
    k_spmm128<false, false, true><<<gS, 256, 0, stream>>>((const u32*)BUF1, row_ptr, col, dinv, b4, d_out, N);
}